// Round 6
// baseline (1119.622 us; speedup 1.0000x reference)
//
#include <hip/hip_runtime.h>
#include <stdint.h>

#define F_IN 512
#define F_HID 256
#define F_OUT 16
#define K_STEPS 10
#define NN 100000
#define EE 3200000

typedef float f32x4 __attribute__((ext_vector_type(4)));
typedef short bf16x8 __attribute__((ext_vector_type(8)));

__device__ __forceinline__ unsigned short f2bf(float f) {
  unsigned u = __builtin_bit_cast(unsigned, f);
  u += 0x7FFFu + ((u >> 16) & 1u);   // RNE
  return (unsigned short)(u >> 16);
}
__device__ __forceinline__ float bf2f(unsigned short s) {
  unsigned u = ((unsigned)s) << 16;
  return __builtin_bit_cast(float, u);
}

// ---- in-degree over targets (self loop handled analytically) ----
__global__ __launch_bounds__(256) void count_kernel(const int* __restrict__ ei,
                                                    int* __restrict__ indeg) {
  int i = blockIdx.x * 256 + threadIdx.x;
  if (i < EE) atomicAdd(&indeg[ei[EE + i]], 1);
}

// ---- CSR offsets via atomic bump (bucket order irrelevant) ----
__global__ __launch_bounds__(256) void offsets_kernel(const int* __restrict__ indeg,
                                                      int* __restrict__ node_off,
                                                      int* __restrict__ total) {
  int i = blockIdx.x * 256 + threadIdx.x;
  if (i < NN) node_off[i] = atomicAdd(total, indeg[i]);
}

// ---- CSR fill: sources bucketed by target ----
__global__ __launch_bounds__(256) void fill_kernel(const int* __restrict__ ei,
                                                   const int* __restrict__ node_off,
                                                   int* __restrict__ fillc,
                                                   int* __restrict__ csr_src) {
  int i = blockIdx.x * 256 + threadIdx.x;
  if (i >= EE) return;
  int r = ei[i];
  int c = ei[EE + i];
  int pos = node_off[c] + atomicAdd(&fillc[c], 1);
  csr_src[pos] = r;
}

// ---- w1 -> bf16 ([256 hidden][512 k], k contiguous = B^T) ----
__global__ __launch_bounds__(256) void convert_w1_kernel(const float* __restrict__ w1,
                                                         unsigned short* __restrict__ w1b) {
  int i = blockIdx.x * 256 + threadIdx.x;
  if (i < F_HID * F_IN) w1b[i] = f2bf(w1[i]);
}

// ---- x -> bf16 (row-major, A-fragments become direct 16B loads) ----
__global__ __launch_bounds__(256) void convert_x_kernel(const float* __restrict__ x,
                                                        unsigned short* __restrict__ xb) {
  size_t i = ((size_t)blockIdx.x * 256 + threadIdx.x) * 8;
  if (i >= (size_t)NN * F_IN) return;
  f32x4 a0 = *(const f32x4*)(x + i);
  f32x4 a1 = *(const f32x4*)(x + i + 4);
  bf16x8 o;
#pragma unroll
  for (int j = 0; j < 4; ++j) { o[j] = (short)f2bf(a0[j]); o[j + 4] = (short)f2bf(a1[j]); }
  *(bf16x8*)(xb + i) = o;
}

// ---- MFMA MLP: h = relu(x@w1.T+b1)@w2.T + b2 ; writes y0 = dinv*h, hterm = 0.1*dinv*h ----
__global__ __launch_bounds__(256) void mlp_kernel(const unsigned short* __restrict__ xb,
                                                  const unsigned short* __restrict__ w1b,
                                                  const float* __restrict__ b1,
                                                  const float* __restrict__ w2,
                                                  const float* __restrict__ b2,
                                                  const int* __restrict__ indeg,
                                                  float* __restrict__ hterm,
                                                  float* __restrict__ y0) {
  __shared__ unsigned short w2s[16][264];      // bf16 w2, padded
  __shared__ unsigned short h1s[4][16][264];   // per-wave relu(h1) strip, bf16

  const int tid = threadIdx.x;
  for (int i = tid; i < F_OUT * F_HID; i += 256) w2s[i >> 8][i & 255] = f2bf(w2[i]);
  __syncthreads();

  const int wave = tid >> 6, l = tid & 63;
  const int lr = l & 15, lk = l >> 4;
  const int m0 = blockIdx.x * 64 + wave * 16;
  const int row = m0 + lr;
  const int rowc = row < NN ? row : (NN - 1);
  const unsigned short* xp  = xb  + (size_t)rowc * F_IN + lk * 8;
  const unsigned short* wp0 = w1b + (size_t)lr * F_IN + lk * 8;

  f32x4 acc[16];
#pragma unroll
  for (int t = 0; t < 16; ++t) acc[t] = (f32x4){0.f, 0.f, 0.f, 0.f};

  bf16x8 af = *(const bf16x8*)xp;              // prefetch ki=0
  for (int ki = 0; ki < 16; ++ki) {
    bf16x8 afn;
    if (ki < 15) afn = *(const bf16x8*)(xp + (ki + 1) * 32);
    const unsigned short* wp = wp0 + ki * 32;
#pragma unroll
    for (int nt = 0; nt < 16; ++nt) {
      bf16x8 bf = *(const bf16x8*)(wp + nt * 16 * F_IN);
      acc[nt] = __builtin_amdgcn_mfma_f32_16x16x32_bf16(af, bf, acc[nt], 0, 0, 0);
    }
    af = afn;
  }

  // epilogue 1: +b1, relu, bf16 -> LDS. D: col=lane&15 (N), row=(lane>>4)*4+reg (M)
#pragma unroll
  for (int nt = 0; nt < 16; ++nt) {
#pragma unroll
    for (int r = 0; r < 4; ++r) {
      int rr = lk * 4 + r, cc = nt * 16 + lr;
      float v = acc[nt][r] + b1[cc];
      v = v > 0.f ? v : 0.f;
      h1s[wave][rr][cc] = f2bf(v);
    }
  }
  __syncthreads();

  // epilogue 2: h2[m][o] = sum_n h1[m][n]*w2[o][n] + b2[o]; lane: m=lr, o=lk*4+j
  float hacc[4];
#pragma unroll
  for (int j = 0; j < 4; ++j) hacc[j] = b2[lk * 4 + j];
  for (int nc = 0; nc < F_HID; nc += 8) {
    bf16x8 hv = *(const bf16x8*)&h1s[wave][lr][nc];
    float hf[8];
#pragma unroll
    for (int q = 0; q < 8; ++q) hf[q] = bf2f((unsigned short)hv[q]);
#pragma unroll
    for (int j = 0; j < 4; ++j) {
      bf16x8 wv = *(const bf16x8*)&w2s[lk * 4 + j][nc];
#pragma unroll
      for (int q = 0; q < 8; ++q) hacc[j] += hf[q] * bf2f((unsigned short)wv[q]);
    }
  }
  if (row < NN) {
    float d  = (float)(indeg[row] + 1);
    float di = rsqrtf(d);
    f32x4 yy = {hacc[0] * di, hacc[1] * di, hacc[2] * di, hacc[3] * di};
    *(f32x4*)(y0 + (size_t)row * F_OUT + lk * 4) = yy;
    f32x4 ht = {yy[0] * 0.1f, yy[1] * 0.1f, yy[2] * 0.1f, yy[3] * 0.1f};
    *(f32x4*)(hterm + (size_t)row * F_OUT + lk * 4) = ht;
  }
}

// ---- one PPR step in y-space: y' = 0.9/d * (sum_in y + y_self) + hterm ----
// 16 lanes per node-PAIR: 2 independent gather chains per group for 2x MLP.
__global__ __launch_bounds__(256) void ppr_kernel(const int* __restrict__ node_off,
                                                  const int* __restrict__ indeg,
                                                  const int* __restrict__ csr_src,
                                                  const float* __restrict__ yin,
                                                  const float* __restrict__ hterm,
                                                  float* __restrict__ yout) {
  int t = blockIdx.x * 256 + threadIdx.x;
  int grp = t >> 4, f = t & 15;
  int g0 = grp * 2, g1 = g0 + 1;
  if (g0 >= NN) return;
  const bool has1 = g1 < NN;
  const int gb = threadIdx.x & 48;

  int s0a = node_off[g0], ca = indeg[g0];
  int s0b = has1 ? node_off[g1] : s0a;
  int cb  = has1 ? indeg[g1] : 0;
  float acc0 = yin[(size_t)g0 * F_OUT + f];        // self loop
  float acc1 = has1 ? yin[(size_t)g1 * F_OUT + f] : 0.f;

  int cmax = ca > cb ? ca : cb;
  for (int base = 0; base < cmax; base += 16) {
    int ia = base + f; ia = ia < ca ? ia : (ca - 1); ia = ia > 0 ? ia : 0;
    int ib = base + f; ib = ib < cb ? ib : (cb - 1); ib = ib > 0 ? ib : 0;
    size_t pa = (size_t)s0a + ia; if (pa >= EE) pa = EE - 1;
    size_t pb = (size_t)s0b + ib; if (pb >= EE) pb = EE - 1;
    int sa = csr_src[pa];
    int sb = csr_src[pb];
#pragma unroll
    for (int j = 0; j < 16; ++j) {
      int na = __shfl(sa, gb + j, 64);
      int nb = __shfl(sb, gb + j, 64);
      float va = yin[(size_t)na * F_OUT + f];
      float vb = yin[(size_t)nb * F_OUT + f];
      if (base + j < ca) acc0 += va;
      if (base + j < cb) acc1 += vb;
    }
  }
  float ra = __builtin_amdgcn_rcpf((float)(ca + 1));
  yout[(size_t)g0 * F_OUT + f] = 0.9f * ra * acc0 + hterm[(size_t)g0 * F_OUT + f];
  if (has1) {
    float rb = __builtin_amdgcn_rcpf((float)(cb + 1));
    yout[(size_t)g1 * F_OUT + f] = 0.9f * rb * acc1 + hterm[(size_t)g1 * F_OUT + f];
  }
}

// ---- output: z = sqrt(d) * y, fp32 ----
__global__ __launch_bounds__(256) void out_kernel(const float* __restrict__ y,
                                                  const int* __restrict__ indeg,
                                                  float* __restrict__ out) {
  int t = blockIdx.x * 256 + threadIdx.x;
  if (t >= NN * F_OUT) return;
  float d = (float)(indeg[t >> 4] + 1);
  out[t] = y[t] * sqrtf(d);
}

extern "C" void kernel_launch(void* const* d_in, const int* in_sizes, int n_in,
                              void* d_out, int out_size, void* d_ws, size_t ws_size,
                              hipStream_t stream) {
  const float* x  = (const float*)d_in[0];
  const float* w1 = (const float*)d_in[1];
  const float* b1 = (const float*)d_in[2];
  const float* w2 = (const float*)d_in[3];
  const float* b2 = (const float*)d_in[4];
  const int*   ei = (const int*)d_in[5];

  char* p = (char*)d_ws;
  auto alloc = [&](size_t bytes) {
    char* r = p;
    p += (bytes + 255) & ~(size_t)255;
    return r;
  };
  float* hterm = (float*)alloc((size_t)NN * F_OUT * 4);
  float* ya    = (float*)alloc((size_t)NN * F_OUT * 4);
  float* yb    = (float*)alloc((size_t)NN * F_OUT * 4);
  unsigned short* w1b = (unsigned short*)alloc((size_t)F_HID * F_IN * 2);
  unsigned short* xb  = (unsigned short*)alloc((size_t)NN * F_IN * 2);
  int* indeg = (int*)alloc(((size_t)2 * NN + 1) * 4);  // indeg | fillc | total
  int* fillc = indeg + NN;
  int* total = fillc + NN;
  int* node_off = (int*)alloc((size_t)NN * 4);
  int* csr_src  = (int*)alloc((size_t)EE * 4);

  hipMemsetAsync(indeg, 0, ((size_t)2 * NN + 1) * 4, stream);

  convert_w1_kernel<<<(F_HID * F_IN + 255) / 256, 256, 0, stream>>>(w1, w1b);
  convert_x_kernel<<<(int)(((size_t)NN * F_IN / 8 + 255) / 256), 256, 0, stream>>>(x, xb);
  count_kernel<<<(EE + 255) / 256, 256, 0, stream>>>(ei, indeg);
  offsets_kernel<<<(NN + 255) / 256, 256, 0, stream>>>(indeg, node_off, total);
  fill_kernel<<<(EE + 255) / 256, 256, 0, stream>>>(ei, node_off, fillc, csr_src);
  mlp_kernel<<<(NN + 63) / 64, 256, 0, stream>>>(xb, w1b, b1, w2, b2, indeg, hterm, ya);

  float* yin = ya;
  float* yout = yb;
  const int ngrp = (NN + 1) / 2;
  for (int k = 0; k < K_STEPS; ++k) {
    ppr_kernel<<<((size_t)ngrp * 16 + 255) / 256, 256, 0, stream>>>(node_off, indeg, csr_src,
                                                                    yin, hterm, yout);
    float* tmp = yin; yin = yout; yout = tmp;
  }
  out_kernel<<<((size_t)NN * 16 + 255) / 256, 256, 0, stream>>>(yin, indeg, (float*)d_out);
}

// Round 7
// 911.155 us; speedup vs baseline: 1.2288x; 1.2288x over previous
//
#include <hip/hip_runtime.h>
#include <stdint.h>

#define F_IN 512
#define F_HID 256
#define F_OUT 16
#define K_STEPS 10
#define NN 100000
#define EE 3200000

typedef float f32x4 __attribute__((ext_vector_type(4)));
typedef float f32x2 __attribute__((ext_vector_type(2)));
typedef short bf16x8 __attribute__((ext_vector_type(8)));
typedef unsigned int u32;
typedef unsigned int u32x2 __attribute__((ext_vector_type(2)));

__device__ __forceinline__ unsigned short f2bf(float f) {
  unsigned u = __builtin_bit_cast(unsigned, f);
  u += 0x7FFFu + ((u >> 16) & 1u);   // RNE
  return (unsigned short)(u >> 16);
}
__device__ __forceinline__ float bf2f(unsigned short s) {
  unsigned u = ((unsigned)s) << 16;
  return __builtin_bit_cast(float, u);
}

// ---- in-degree over targets (self loop handled analytically) ----
__global__ __launch_bounds__(256) void count_kernel(const int* __restrict__ ei,
                                                    int* __restrict__ indeg) {
  int i = blockIdx.x * 256 + threadIdx.x;
  if (i < EE) atomicAdd(&indeg[ei[EE + i]], 1);
}

// ---- CSR offsets via atomic bump (bucket order irrelevant) ----
__global__ __launch_bounds__(256) void offsets_kernel(const int* __restrict__ indeg,
                                                      int* __restrict__ node_off,
                                                      int* __restrict__ total) {
  int i = blockIdx.x * 256 + threadIdx.x;
  if (i < NN) node_off[i] = atomicAdd(total, indeg[i]);
}

// ---- CSR fill: sources bucketed by target ----
__global__ __launch_bounds__(256) void fill_kernel(const int* __restrict__ ei,
                                                   const int* __restrict__ node_off,
                                                   int* __restrict__ fillc,
                                                   int* __restrict__ csr_src) {
  int i = blockIdx.x * 256 + threadIdx.x;
  if (i >= EE) return;
  int r = ei[i];
  int c = ei[EE + i];
  int pos = node_off[c] + atomicAdd(&fillc[c], 1);
  csr_src[pos] = r;
}

// ---- w1 -> bf16 ([256 hidden][512 k], k contiguous = B^T) ----
__global__ __launch_bounds__(256) void convert_w1_kernel(const float* __restrict__ w1,
                                                         unsigned short* __restrict__ w1b) {
  int i = blockIdx.x * 256 + threadIdx.x;
  if (i < F_HID * F_IN) w1b[i] = f2bf(w1[i]);
}

// ---- x -> bf16 (row-major, A-fragments become direct 16B loads) ----
__global__ __launch_bounds__(256) void convert_x_kernel(const float* __restrict__ x,
                                                        unsigned short* __restrict__ xb) {
  size_t i = ((size_t)blockIdx.x * 256 + threadIdx.x) * 8;
  if (i >= (size_t)NN * F_IN) return;
  f32x4 a0 = *(const f32x4*)(x + i);
  f32x4 a1 = *(const f32x4*)(x + i + 4);
  bf16x8 o;
#pragma unroll
  for (int j = 0; j < 4; ++j) { o[j] = (short)f2bf(a0[j]); o[j + 4] = (short)f2bf(a1[j]); }
  *(bf16x8*)(xb + i) = o;
}

// ---- MFMA MLP: writes y0 (packed bf16 pairs) and hterm = 0.1*dinv*h (fp32) ----
// Register-double-buffered B fragments: 16 loads in flight per k-step.
__global__ __launch_bounds__(256, 2) void mlp_kernel(const unsigned short* __restrict__ xb,
                                                     const unsigned short* __restrict__ w1b,
                                                     const float* __restrict__ b1,
                                                     const float* __restrict__ w2,
                                                     const float* __restrict__ b2,
                                                     const int* __restrict__ indeg,
                                                     float* __restrict__ hterm,
                                                     u32* __restrict__ y0) {
  __shared__ unsigned short w2s[16][264];      // bf16 w2, padded
  __shared__ unsigned short h1s[4][16][264];   // per-wave relu(h1) strip, bf16

  const int tid = threadIdx.x;
  for (int i = tid; i < F_OUT * F_HID; i += 256) w2s[i >> 8][i & 255] = f2bf(w2[i]);
  __syncthreads();

  const int wave = tid >> 6, l = tid & 63;
  const int lr = l & 15, lk = l >> 4;
  const int m0 = blockIdx.x * 64 + wave * 16;
  const int row = m0 + lr;
  const int rowc = row < NN ? row : (NN - 1);
  const unsigned short* xp  = xb  + (size_t)rowc * F_IN + lk * 8;
  const unsigned short* wp0 = w1b + (size_t)lr * F_IN + lk * 8;

  f32x4 acc[16];
#pragma unroll
  for (int t = 0; t < 16; ++t) acc[t] = (f32x4){0.f, 0.f, 0.f, 0.f};

  bf16x8 bA[16], bB[16];
  bf16x8 aA, aB;
  aA = *(const bf16x8*)xp;
#pragma unroll
  for (int nt = 0; nt < 16; ++nt) bA[nt] = *(const bf16x8*)(wp0 + nt * 16 * F_IN);

#pragma unroll
  for (int kk = 0; kk < 8; ++kk) {
    // even step ki=2kk: compute with aA/bA, prefetch ki=2kk+1 into aB/bB
    {
      const unsigned short* wpn = wp0 + (2 * kk + 1) * 32;
      aB = *(const bf16x8*)(xp + (2 * kk + 1) * 32);
#pragma unroll
      for (int nt = 0; nt < 16; ++nt) {
        bB[nt] = *(const bf16x8*)(wpn + nt * 16 * F_IN);
        acc[nt] = __builtin_amdgcn_mfma_f32_16x16x32_bf16(aA, bA[nt], acc[nt], 0, 0, 0);
      }
    }
    // odd step ki=2kk+1: compute with aB/bB, prefetch ki=2kk+2 into aA/bA
    {
      const unsigned short* wpn = wp0 + (2 * kk + 2) * 32;
      if (kk < 7) aA = *(const bf16x8*)(xp + (2 * kk + 2) * 32);
#pragma unroll
      for (int nt = 0; nt < 16; ++nt) {
        if (kk < 7) bA[nt] = *(const bf16x8*)(wpn + nt * 16 * F_IN);
        acc[nt] = __builtin_amdgcn_mfma_f32_16x16x32_bf16(aB, bB[nt], acc[nt], 0, 0, 0);
      }
    }
  }

  // epilogue 1: +b1, relu, bf16 -> LDS. D: col=lane&15 (N), row=(lane>>4)*4+reg (M)
#pragma unroll
  for (int nt = 0; nt < 16; ++nt) {
#pragma unroll
    for (int r = 0; r < 4; ++r) {
      int rr = lk * 4 + r, cc = nt * 16 + lr;
      float v = acc[nt][r] + b1[cc];
      v = v > 0.f ? v : 0.f;
      h1s[wave][rr][cc] = f2bf(v);
    }
  }
  __syncthreads();

  // epilogue 2: h2[m][o] = sum_n h1[m][n]*w2[o][n] + b2[o]; lane: m=lr, o=lk*4+j
  float hacc[4];
#pragma unroll
  for (int j = 0; j < 4; ++j) hacc[j] = b2[lk * 4 + j];
  for (int nc = 0; nc < F_HID; nc += 8) {
    bf16x8 hv = *(const bf16x8*)&h1s[wave][lr][nc];
    float hf[8];
#pragma unroll
    for (int q = 0; q < 8; ++q) hf[q] = bf2f((unsigned short)hv[q]);
#pragma unroll
    for (int j = 0; j < 4; ++j) {
      bf16x8 wv = *(const bf16x8*)&w2s[lk * 4 + j][nc];
#pragma unroll
      for (int q = 0; q < 8; ++q) hacc[j] += hf[q] * bf2f((unsigned short)wv[q]);
    }
  }
  if (row < NN) {
    float d  = (float)(indeg[row] + 1);
    float di = rsqrtf(d);
    f32x4 yy = {hacc[0] * di, hacc[1] * di, hacc[2] * di, hacc[3] * di};
    // y0 packed: word w = features {2w, 2w+1}; lane covers words lk*2, lk*2+1
    u32x2 pw = {(u32)f2bf(yy[0]) | ((u32)f2bf(yy[1]) << 16),
                (u32)f2bf(yy[2]) | ((u32)f2bf(yy[3]) << 16)};
    *(u32x2*)(y0 + (size_t)row * 8 + lk * 2) = pw;
    f32x4 ht = {yy[0] * 0.1f, yy[1] * 0.1f, yy[2] * 0.1f, yy[3] * 0.1f};
    *(f32x4*)(hterm + (size_t)row * F_OUT + lk * 4) = ht;
  }
}

// ---- one PPR step in y-space (packed bf16): y' = 0.9/d*(sum_in y + y_self) + hterm ----
// 8 lanes per node-pair word-slice: lane f2 covers features {2f2, 2f2+1}.
__global__ __launch_bounds__(256) void ppr_kernel(const int* __restrict__ node_off,
                                                  const int* __restrict__ indeg,
                                                  const int* __restrict__ csr_src,
                                                  const u32* __restrict__ yin,
                                                  const float* __restrict__ hterm,
                                                  u32* __restrict__ yout) {
  int t = blockIdx.x * 256 + threadIdx.x;
  int grp = t >> 3, f2 = t & 7;
  int g0 = grp * 2, g1 = g0 + 1;
  if (g0 >= NN) return;
  const bool has1 = g1 < NN;
  const int gb = threadIdx.x & 56;          // 8-lane group base within wave

  int s0a = node_off[g0], ca = indeg[g0];
  int s0b = has1 ? node_off[g1] : s0a;
  int cb  = has1 ? indeg[g1] : 0;

  u32 sw = yin[(size_t)g0 * 8 + f2];        // self loop
  float a0l = bf2f((unsigned short)(sw & 0xffff));
  float a0h = bf2f((unsigned short)(sw >> 16));
  float a1l = 0.f, a1h = 0.f;
  if (has1) {
    u32 sw1 = yin[(size_t)g1 * 8 + f2];
    a1l = bf2f((unsigned short)(sw1 & 0xffff));
    a1h = bf2f((unsigned short)(sw1 >> 16));
  }

  int cmax = ca > cb ? ca : cb;
  for (int base = 0; base < cmax; base += 8) {
    int ia = base + f2; ia = ia < ca ? ia : (ca - 1); ia = ia > 0 ? ia : 0;
    int ib = base + f2; ib = ib < cb ? ib : (cb - 1); ib = ib > 0 ? ib : 0;
    size_t pa = (size_t)s0a + ia; if (pa >= EE) pa = EE - 1;
    size_t pb = (size_t)s0b + ib; if (pb >= EE) pb = EE - 1;
    int sa = csr_src[pa];
    int sb = csr_src[pb];
#pragma unroll
    for (int j = 0; j < 8; ++j) {
      int na = __shfl(sa, gb + j, 64);
      int nb = __shfl(sb, gb + j, 64);
      u32 va = yin[(size_t)na * 8 + f2];
      u32 vb = yin[(size_t)nb * 8 + f2];
      if (base + j < ca) {
        a0l += bf2f((unsigned short)(va & 0xffff));
        a0h += bf2f((unsigned short)(va >> 16));
      }
      if (base + j < cb) {
        a1l += bf2f((unsigned short)(vb & 0xffff));
        a1h += bf2f((unsigned short)(vb >> 16));
      }
    }
  }
  {
    float ra = 0.9f * __builtin_amdgcn_rcpf((float)(ca + 1));
    f32x2 ht = *(const f32x2*)(hterm + (size_t)g0 * F_OUT + f2 * 2);
    float lo = ra * a0l + ht[0];
    float hi = ra * a0h + ht[1];
    yout[(size_t)g0 * 8 + f2] = (u32)f2bf(lo) | ((u32)f2bf(hi) << 16);
  }
  if (has1) {
    float rb = 0.9f * __builtin_amdgcn_rcpf((float)(cb + 1));
    f32x2 ht = *(const f32x2*)(hterm + (size_t)g1 * F_OUT + f2 * 2);
    float lo = rb * a1l + ht[0];
    float hi = rb * a1h + ht[1];
    yout[(size_t)g1 * 8 + f2] = (u32)f2bf(lo) | ((u32)f2bf(hi) << 16);
  }
}

// ---- output: z = sqrt(d) * y, unpack bf16 -> fp32 ----
__global__ __launch_bounds__(256) void out_kernel(const u32* __restrict__ y,
                                                  const int* __restrict__ indeg,
                                                  float* __restrict__ out) {
  int t = blockIdx.x * 256 + threadIdx.x;
  if (t >= NN * 8) return;
  float sd = sqrtf((float)(indeg[t >> 3] + 1));
  u32 w = y[t];
  f32x2 o = {bf2f((unsigned short)(w & 0xffff)) * sd,
             bf2f((unsigned short)(w >> 16)) * sd};
  *(f32x2*)(out + (size_t)t * 2) = o;
}

extern "C" void kernel_launch(void* const* d_in, const int* in_sizes, int n_in,
                              void* d_out, int out_size, void* d_ws, size_t ws_size,
                              hipStream_t stream) {
  const float* x  = (const float*)d_in[0];
  const float* w1 = (const float*)d_in[1];
  const float* b1 = (const float*)d_in[2];
  const float* w2 = (const float*)d_in[3];
  const float* b2 = (const float*)d_in[4];
  const int*   ei = (const int*)d_in[5];

  char* p = (char*)d_ws;
  auto alloc = [&](size_t bytes) {
    char* r = p;
    p += (bytes + 255) & ~(size_t)255;
    return r;
  };
  float* hterm = (float*)alloc((size_t)NN * F_OUT * 4);
  u32* ya = (u32*)alloc((size_t)NN * 8 * 4);
  u32* yb = (u32*)alloc((size_t)NN * 8 * 4);
  unsigned short* w1b = (unsigned short*)alloc((size_t)F_HID * F_IN * 2);
  unsigned short* xb  = (unsigned short*)alloc((size_t)NN * F_IN * 2);
  int* indeg = (int*)alloc(((size_t)2 * NN + 1) * 4);  // indeg | fillc | total
  int* fillc = indeg + NN;
  int* total = fillc + NN;
  int* node_off = (int*)alloc((size_t)NN * 4);
  int* csr_src  = (int*)alloc((size_t)EE * 4);

  hipMemsetAsync(indeg, 0, ((size_t)2 * NN + 1) * 4, stream);

  convert_w1_kernel<<<(F_HID * F_IN + 255) / 256, 256, 0, stream>>>(w1, w1b);
  convert_x_kernel<<<(int)(((size_t)NN * F_IN / 8 + 255) / 256), 256, 0, stream>>>(x, xb);
  count_kernel<<<(EE + 255) / 256, 256, 0, stream>>>(ei, indeg);
  offsets_kernel<<<(NN + 255) / 256, 256, 0, stream>>>(indeg, node_off, total);
  fill_kernel<<<(EE + 255) / 256, 256, 0, stream>>>(ei, node_off, fillc, csr_src);
  mlp_kernel<<<(NN + 63) / 64, 256, 0, stream>>>(xb, w1b, b1, w2, b2, indeg, hterm, ya);

  u32* yin = ya;
  u32* yout = yb;
  const int ngrp = (NN + 1) / 2;
  for (int k = 0; k < K_STEPS; ++k) {
    ppr_kernel<<<((size_t)ngrp * 8 + 255) / 256, 256, 0, stream>>>(node_off, indeg, csr_src,
                                                                   yin, hterm, yout);
    u32* tmp = yin; yin = yout; yout = tmp;
  }
  out_kernel<<<((size_t)NN * 8 + 255) / 256, 256, 0, stream>>>(yin, indeg, (float*)d_out);
}

// Round 8
// 734.478 us; speedup vs baseline: 1.5244x; 1.2405x over previous
//
#include <hip/hip_runtime.h>
#include <stdint.h>

#define F_IN 512
#define F_HID 256
#define F_OUT 16
#define K_STEPS 10
#define NN 100000
#define EE 3200000

typedef float f32x4 __attribute__((ext_vector_type(4)));
typedef float f32x2 __attribute__((ext_vector_type(2)));
typedef short bf16x8 __attribute__((ext_vector_type(8)));
typedef unsigned int u32;

__device__ __forceinline__ unsigned short f2bf(float f) {
  unsigned u = __builtin_bit_cast(unsigned, f);
  u += 0x7FFFu + ((u >> 16) & 1u);   // RNE
  return (unsigned short)(u >> 16);
}
__device__ __forceinline__ float bf2f(unsigned short s) {
  unsigned u = ((unsigned)s) << 16;
  return __builtin_bit_cast(float, u);
}
__device__ __forceinline__ int pad_cnt(int deg) { return (deg + 15) & ~7; }

// ---- in-degree over targets (self loop handled analytically) ----
__global__ __launch_bounds__(256) void count_kernel(const int* __restrict__ ei,
                                                    int* __restrict__ indeg) {
  int i = blockIdx.x * 256 + threadIdx.x;
  if (i < EE) atomicAdd(&indeg[ei[EE + i]], 1);
}

// ---- CSR offsets (padded so every node ends with a fully-sentinel 8-chunk) ----
__global__ __launch_bounds__(256) void offsets_kernel(const int* __restrict__ indeg,
                                                      int* __restrict__ node_off,
                                                      int* __restrict__ total) {
  int i = blockIdx.x * 256 + threadIdx.x;
  if (i < NN) node_off[i] = atomicAdd(total, pad_cnt(indeg[i]));
}

// ---- CSR fill: sources bucketed by target ----
__global__ __launch_bounds__(256) void fill_kernel(const int* __restrict__ ei,
                                                   const int* __restrict__ node_off,
                                                   int* __restrict__ fillc,
                                                   int* __restrict__ csr_src) {
  int i = blockIdx.x * 256 + threadIdx.x;
  if (i >= EE) return;
  int r = ei[i];
  int c = ei[EE + i];
  int pos = node_off[c] + atomicAdd(&fillc[c], 1);
  csr_src[pos] = r;
}

// ---- pad slots -> sentinel NN; zero sentinel y rows ----
__global__ __launch_bounds__(256) void pad_kernel(const int* __restrict__ indeg,
                                                  const int* __restrict__ node_off,
                                                  int* __restrict__ csr_src,
                                                  u32* __restrict__ ya, u32* __restrict__ yb) {
  int i = blockIdx.x * 256 + threadIdx.x;
  if (i < NN) {
    int deg = indeg[i], off = node_off[i], pc = pad_cnt(deg);
    for (int s = deg; s < pc; ++s) csr_src[off + s] = NN;
  }
  if (i < 8)            ya[(size_t)NN * 8 + i] = 0;
  else if (i < 16)      yb[(size_t)NN * 8 + (i - 8)] = 0;
}

// ---- w1 -> bf16 ([256 hidden][512 k], k contiguous) ----
__global__ __launch_bounds__(256) void convert_w1_kernel(const float* __restrict__ w1,
                                                         unsigned short* __restrict__ w1b) {
  int i = blockIdx.x * 256 + threadIdx.x;
  if (i < F_HID * F_IN) w1b[i] = f2bf(w1[i]);
}

// ---- x -> bf16 row-major ----
__global__ __launch_bounds__(256) void convert_x_kernel(const float* __restrict__ x,
                                                        unsigned short* __restrict__ xb) {
  size_t i = ((size_t)blockIdx.x * 256 + threadIdx.x) * 8;
  if (i >= (size_t)NN * F_IN) return;
  f32x4 a0 = *(const f32x4*)(x + i);
  f32x4 a1 = *(const f32x4*)(x + i + 4);
  bf16x8 o;
#pragma unroll
  for (int j = 0; j < 4; ++j) { o[j] = (short)f2bf(a0[j]); o[j + 4] = (short)f2bf(a1[j]); }
  *(bf16x8*)(xb + i) = o;
}

// ---- MFMA MLP, m97-style: 64x256 block tile, 4 waves x (64x64), LDS dbuf staging ----
#define BM 64
#define BKC 32                 // k per chunk
#define NCH (F_IN / BKC)       // 16
#define AST 80                 // A row stride bytes (64 data + 16 pad)
#define BST 80                 // B col-row stride bytes
#define ABYT (BM * AST)        // 5120
#define BBYT (F_HID * BST)     // 20480
#define PBYT (ABYT + BBYT)     // 25600
__global__ __launch_bounds__(256) void mlp_kernel(const unsigned short* __restrict__ xb,
                                                  const unsigned short* __restrict__ w1b,
                                                  const float* __restrict__ b1,
                                                  const float* __restrict__ w2,
                                                  const float* __restrict__ b2,
                                                  const int* __restrict__ indeg,
                                                  float* __restrict__ hterm,
                                                  u32* __restrict__ y0) {
  __shared__ char lds[2 * PBYT];   // 51200 B; epilogue overlay: h1[64][264] + w2s[16][264]
  const int tid = threadIdx.x;
  const int wv = tid >> 6, l = tid & 63;
  const int lr = l & 15, lk = l >> 4;
  const int m0 = blockIdx.x * BM;

  // 5 staging slots/thread: slots 0..255 = A (row,q), 256..1279 = B (col,q); 16B each
  const unsigned short* gsrc[5];
  int lofs[5];
#pragma unroll
  for (int i = 0; i < 5; ++i) {
    int s = tid + i * 256;
    if (s < 256) {
      int row = s >> 2, q = s & 3;
      int gr = m0 + row; if (gr >= NN) gr = NN - 1;
      gsrc[i] = xb + (size_t)gr * F_IN + q * 8;
      lofs[i] = row * AST + q * 16;
    } else {
      int sb = s - 256, col = sb >> 2, q = sb & 3;
      gsrc[i] = w1b + (size_t)col * F_IN + q * 8;
      lofs[i] = ABYT + col * BST + q * 16;
    }
  }

  f32x4 acc[4][4];
#pragma unroll
  for (int a = 0; a < 4; ++a)
#pragma unroll
    for (int b = 0; b < 4; ++b) acc[a][b] = (f32x4){0.f, 0.f, 0.f, 0.f};

  bf16x8 rg[5];
#pragma unroll
  for (int i = 0; i < 5; ++i) rg[i] = *(const bf16x8*)(gsrc[i]);
#pragma unroll
  for (int i = 0; i < 5; ++i) *(bf16x8*)(lds + lofs[i]) = rg[i];
  __syncthreads();

  for (int c = 0; c < NCH; ++c) {
    char* buf = lds + (c & 1) * PBYT;
    if (c < NCH - 1) {
#pragma unroll
      for (int i = 0; i < 5; ++i) rg[i] = *(const bf16x8*)(gsrc[i] + (c + 1) * BKC);
    }
    bf16x8 af[4], bfr[4];
#pragma unroll
    for (int fm = 0; fm < 4; ++fm)
      af[fm] = *(const bf16x8*)(buf + (fm * 16 + lr) * AST + lk * 16);
#pragma unroll
    for (int fn = 0; fn < 4; ++fn)
      bfr[fn] = *(const bf16x8*)(buf + ABYT + (wv * 64 + fn * 16 + lr) * BST + lk * 16);
#pragma unroll
    for (int fm = 0; fm < 4; ++fm)
#pragma unroll
      for (int fn = 0; fn < 4; ++fn)
        acc[fm][fn] = __builtin_amdgcn_mfma_f32_16x16x32_bf16(af[fm], bfr[fn], acc[fm][fn],
                                                              0, 0, 0);
    if (c < NCH - 1) {
      char* nbuf = lds + ((c + 1) & 1) * PBYT;
#pragma unroll
      for (int i = 0; i < 5; ++i) *(bf16x8*)(nbuf + lofs[i]) = rg[i];
    }
    __syncthreads();
  }

  // ---- epilogue 1: +b1, relu -> h1 overlay [64][264] bf16; w2 -> bf16 [16][264] ----
  unsigned short* h1p = (unsigned short*)lds;
  unsigned short* w2p = (unsigned short*)(lds + 64 * 264 * 2);   // 33792
#pragma unroll
  for (int fn = 0; fn < 4; ++fn) {
    int col = wv * 64 + fn * 16 + lr;
    float bb = b1[col];
#pragma unroll
    for (int fm = 0; fm < 4; ++fm) {
#pragma unroll
      for (int r = 0; r < 4; ++r) {
        float v = acc[fm][fn][r] + bb;
        v = v > 0.f ? v : 0.f;
        h1p[(fm * 16 + lk * 4 + r) * 264 + col] = f2bf(v);
      }
    }
  }
  for (int i = tid; i < 16 * 256; i += 256) w2p[(i >> 8) * 264 + (i & 255)] = f2bf(w2[i]);
  __syncthreads();

  // ---- GEMM2 via MFMA: wave wv -> rows wv*16..+16, all 16 outputs ----
  f32x4 acc2 = (f32x4){0.f, 0.f, 0.f, 0.f};
#pragma unroll
  for (int ks = 0; ks < 8; ++ks) {
    bf16x8 a2 = *(const bf16x8*)&h1p[(wv * 16 + lr) * 264 + ks * 32 + lk * 8];
    bf16x8 b2f = *(const bf16x8*)&w2p[lr * 264 + ks * 32 + lk * 8];
    acc2 = __builtin_amdgcn_mfma_f32_16x16x32_bf16(a2, b2f, acc2, 0, 0, 0);
  }
  // D2: out row = wv*16 + lk*4 + r, o = lr
  float bb2 = b2[lr];
#pragma unroll
  for (int r = 0; r < 4; ++r) {
    int row = m0 + wv * 16 + lk * 4 + r;
    if (row < NN) {
      float d = (float)(indeg[row] + 1);
      float di = rsqrtf(d);
      float v = (acc2[r] + bb2) * di;            // y0 value
      hterm[(size_t)row * F_OUT + lr] = 0.1f * v;
      float vo = __shfl_xor(v, 1, 64);           // partner feature (lr^1), same row
      if ((lr & 1) == 0) {
        u32 pw = (u32)f2bf(v) | ((u32)f2bf(vo) << 16);
        y0[(size_t)row * 8 + (lr >> 1)] = pw;
      }
    }
  }
}

// ---- one PPR step in y-space (packed bf16): y' = 0.9/d*(sum_in y + y_self) + hterm ----
// 8 lanes per node-pair; sentinel-padded CSR -> unconditional inner loop; csr prefetch.
__global__ __launch_bounds__(256) void ppr_kernel(const int* __restrict__ node_off,
                                                  const int* __restrict__ indeg,
                                                  const int* __restrict__ csr_src,
                                                  const u32* __restrict__ yin,
                                                  const float* __restrict__ hterm,
                                                  u32* __restrict__ yout) {
  int t = blockIdx.x * 256 + threadIdx.x;
  int grp = t >> 3, f2 = t & 7;
  int g0 = grp * 2, g1 = g0 + 1;
  if (g0 >= NN) return;
  const bool has1 = g1 < NN;
  const int gb = threadIdx.x & 56;

  int ca = indeg[g0], s0a = node_off[g0];
  int cb = has1 ? indeg[g1] : 0;
  int s0b = has1 ? node_off[g1] : s0a;
  int pa = pad_cnt(ca), pb = pad_cnt(cb);      // >= 8; final 8-chunk all-sentinel

  u32 sw0 = yin[(size_t)g0 * 8 + f2];
  float a0l = bf2f((unsigned short)(sw0 & 0xffff));
  float a0h = bf2f((unsigned short)(sw0 >> 16));
  float a1l = 0.f, a1h = 0.f;
  if (has1) {
    u32 sw1 = yin[(size_t)g1 * 8 + f2];
    a1l = bf2f((unsigned short)(sw1 & 0xffff));
    a1h = bf2f((unsigned short)(sw1 >> 16));
  }

  int cmax = pa > pb ? pa : pb;
  int sa = csr_src[s0a + f2];
  int sb = csr_src[s0b + f2];
  for (int base = 0; base < cmax; base += 8) {
    int nb2 = base + 8;
    int oa = nb2 < pa - 8 ? nb2 : pa - 8;      // clamp to own all-sentinel tail chunk
    int ob = nb2 < pb - 8 ? nb2 : pb - 8;
    int sa_n = csr_src[s0a + oa + f2];         // prefetch next chunk
    int sb_n = csr_src[s0b + ob + f2];
#pragma unroll
    for (int j = 0; j < 8; ++j) {
      int na = __shfl(sa, gb + j, 64);
      int nb = __shfl(sb, gb + j, 64);
      u32 va = yin[(size_t)na * 8 + f2];
      u32 vb = yin[(size_t)nb * 8 + f2];
      a0l += bf2f((unsigned short)(va & 0xffff));
      a0h += bf2f((unsigned short)(va >> 16));
      a1l += bf2f((unsigned short)(vb & 0xffff));
      a1h += bf2f((unsigned short)(vb >> 16));
    }
    sa = sa_n; sb = sb_n;
  }
  {
    float ra = 0.9f * __builtin_amdgcn_rcpf((float)(ca + 1));
    f32x2 ht = *(const f32x2*)(hterm + (size_t)g0 * F_OUT + f2 * 2);
    yout[(size_t)g0 * 8 + f2] = (u32)f2bf(ra * a0l + ht[0]) |
                                ((u32)f2bf(ra * a0h + ht[1]) << 16);
  }
  if (has1) {
    float rb = 0.9f * __builtin_amdgcn_rcpf((float)(cb + 1));
    f32x2 ht = *(const f32x2*)(hterm + (size_t)g1 * F_OUT + f2 * 2);
    yout[(size_t)g1 * 8 + f2] = (u32)f2bf(rb * a1l + ht[0]) |
                                ((u32)f2bf(rb * a1h + ht[1]) << 16);
  }
}

// ---- output: z = sqrt(d) * y, unpack bf16 -> fp32 ----
__global__ __launch_bounds__(256) void out_kernel(const u32* __restrict__ y,
                                                  const int* __restrict__ indeg,
                                                  float* __restrict__ out) {
  int t = blockIdx.x * 256 + threadIdx.x;
  if (t >= NN * 8) return;
  float sd = sqrtf((float)(indeg[t >> 3] + 1));
  u32 w = y[t];
  f32x2 o = {bf2f((unsigned short)(w & 0xffff)) * sd,
             bf2f((unsigned short)(w >> 16)) * sd};
  *(f32x2*)(out + (size_t)t * 2) = o;
}

extern "C" void kernel_launch(void* const* d_in, const int* in_sizes, int n_in,
                              void* d_out, int out_size, void* d_ws, size_t ws_size,
                              hipStream_t stream) {
  const float* x  = (const float*)d_in[0];
  const float* w1 = (const float*)d_in[1];
  const float* b1 = (const float*)d_in[2];
  const float* w2 = (const float*)d_in[3];
  const float* b2 = (const float*)d_in[4];
  const int*   ei = (const int*)d_in[5];

  char* p = (char*)d_ws;
  auto alloc = [&](size_t bytes) {
    char* r = p;
    p += (bytes + 255) & ~(size_t)255;
    return r;
  };
  float* hterm = (float*)alloc((size_t)NN * F_OUT * 4);
  u32* ya = (u32*)alloc((size_t)(NN + 1) * 8 * 4);
  u32* yb = (u32*)alloc((size_t)(NN + 1) * 8 * 4);
  unsigned short* w1b = (unsigned short*)alloc((size_t)F_HID * F_IN * 2);
  unsigned short* xb  = (unsigned short*)alloc((size_t)NN * F_IN * 2);
  int* indeg = (int*)alloc(((size_t)2 * NN + 1) * 4);  // indeg | fillc | total
  int* fillc = indeg + NN;
  int* total = fillc + NN;
  int* node_off = (int*)alloc((size_t)NN * 4);
  int* csr_src  = (int*)alloc(((size_t)EE + (size_t)NN * 16) * 4);

  hipMemsetAsync(indeg, 0, ((size_t)2 * NN + 1) * 4, stream);

  convert_w1_kernel<<<(F_HID * F_IN + 255) / 256, 256, 0, stream>>>(w1, w1b);
  convert_x_kernel<<<(int)(((size_t)NN * F_IN / 8 + 255) / 256), 256, 0, stream>>>(x, xb);
  count_kernel<<<(EE + 255) / 256, 256, 0, stream>>>(ei, indeg);
  offsets_kernel<<<(NN + 255) / 256, 256, 0, stream>>>(indeg, node_off, total);
  fill_kernel<<<(EE + 255) / 256, 256, 0, stream>>>(ei, node_off, fillc, csr_src);
  pad_kernel<<<(NN + 255) / 256, 256, 0, stream>>>(indeg, node_off, csr_src, ya, yb);
  mlp_kernel<<<(NN + BM - 1) / BM, 256, 0, stream>>>(xb, w1b, b1, w2, b2, indeg, hterm, ya);

  u32* yin = ya;
  u32* yout = yb;
  const int ngrp = (NN + 1) / 2;
  for (int k = 0; k < K_STEPS; ++k) {
    ppr_kernel<<<((size_t)ngrp * 8 + 255) / 256, 256, 0, stream>>>(node_off, indeg, csr_src,
                                                                   yin, hterm, yout);
    u32* tmp = yin; yin = yout; yout = tmp;
  }
  out_kernel<<<((size_t)NN * 8 + 255) / 256, 256, 0, stream>>>(yin, indeg, (float*)d_out);
}

// Round 9
// 695.906 us; speedup vs baseline: 1.6089x; 1.0554x over previous
//
#include <hip/hip_runtime.h>
#include <stdint.h>

#define F_IN 512
#define F_HID 256
#define F_OUT 16
#define K_STEPS 10
#define NN 100000
#define EE 3200000

typedef float f32x4 __attribute__((ext_vector_type(4)));
typedef float f32x2 __attribute__((ext_vector_type(2)));
typedef short bf16x8 __attribute__((ext_vector_type(8)));
typedef unsigned int u32;
typedef unsigned int u32x4 __attribute__((ext_vector_type(4)));

__device__ __forceinline__ unsigned short f2bf(float f) {
  unsigned u = __builtin_bit_cast(unsigned, f);
  u += 0x7FFFu + ((u >> 16) & 1u);   // RNE
  return (unsigned short)(u >> 16);
}
__device__ __forceinline__ float bf2f(unsigned short s) {
  unsigned u = ((unsigned)s) << 16;
  return __builtin_bit_cast(float, u);
}
__device__ __forceinline__ float bflo(u32 w) {           // low bf16 -> f32
  return __builtin_bit_cast(float, w << 16);
}
__device__ __forceinline__ float bfhi(u32 w) {           // high bf16 -> f32
  return __builtin_bit_cast(float, w & 0xffff0000u);
}
__device__ __forceinline__ int pad_cnt(int deg) { return (deg + 3) & ~3; }

// ---- in-degree over targets (self loop handled analytically) ----
__global__ __launch_bounds__(256) void count_kernel(const int* __restrict__ ei,
                                                    int* __restrict__ indeg) {
  int i = blockIdx.x * 256 + threadIdx.x;
  if (i < EE) atomicAdd(&indeg[ei[EE + i]], 1);
}

// ---- CSR offsets (padded to multiple of 4 per node) ----
__global__ __launch_bounds__(256) void offsets_kernel(const int* __restrict__ indeg,
                                                      int* __restrict__ node_off,
                                                      int* __restrict__ total) {
  int i = blockIdx.x * 256 + threadIdx.x;
  if (i < NN) node_off[i] = atomicAdd(total, pad_cnt(indeg[i]));
}

// ---- CSR fill: sources bucketed by target ----
__global__ __launch_bounds__(256) void fill_kernel(const int* __restrict__ ei,
                                                   const int* __restrict__ node_off,
                                                   int* __restrict__ fillc,
                                                   int* __restrict__ csr_src) {
  int i = blockIdx.x * 256 + threadIdx.x;
  if (i >= EE) return;
  int r = ei[i];
  int c = ei[EE + i];
  int pos = node_off[c] + atomicAdd(&fillc[c], 1);
  csr_src[pos] = r;
}

// ---- pad slots -> sentinel NN (max 3 per node); zero sentinel y rows ----
__global__ __launch_bounds__(256) void pad_kernel(const int* __restrict__ indeg,
                                                  const int* __restrict__ node_off,
                                                  int* __restrict__ csr_src,
                                                  u32* __restrict__ ya, u32* __restrict__ yb) {
  int i = blockIdx.x * 256 + threadIdx.x;
  if (i < NN) {
    int deg = indeg[i], off = node_off[i], pc = pad_cnt(deg);
    for (int s = deg; s < pc; ++s) csr_src[off + s] = NN;
  }
  if (i < 8)            ya[(size_t)NN * 8 + i] = 0;
  else if (i < 16)      yb[(size_t)NN * 8 + (i - 8)] = 0;
}

// ---- w1 -> bf16 ([256 hidden][512 k], k contiguous) ----
__global__ __launch_bounds__(256) void convert_w1_kernel(const float* __restrict__ w1,
                                                         unsigned short* __restrict__ w1b) {
  int i = blockIdx.x * 256 + threadIdx.x;
  if (i < F_HID * F_IN) w1b[i] = f2bf(w1[i]);
}

// ---- MFMA MLP (x-conversion fused into staging): 64x256 tile, 4 waves x (64x64) ----
#define BM 64
#define BKC 32
#define NCH (F_IN / BKC)       // 16
#define AST 80
#define BST 80
#define ABYT (BM * AST)        // 5120
#define BBYT (F_HID * BST)     // 20480
#define PBYT (ABYT + BBYT)     // 25600
__global__ __launch_bounds__(256) void mlp_kernel(const float* __restrict__ x,
                                                  const unsigned short* __restrict__ w1b,
                                                  const float* __restrict__ b1,
                                                  const float* __restrict__ w2,
                                                  const float* __restrict__ b2,
                                                  const int* __restrict__ indeg,
                                                  float* __restrict__ hterm,
                                                  u32* __restrict__ y0) {
  __shared__ char lds[2 * PBYT];   // 51200 B; epilogue overlay: h1[64][264] + w2s[16][264]
  const int tid = threadIdx.x;
  const int wv = tid >> 6, l = tid & 63;
  const int lr = l & 15, lk = l >> 4;
  const int m0 = blockIdx.x * BM;

  // slot 0 = A (f32 source, cvt in reg), slots 1..4 = B (bf16 source)
  const int rowA = tid >> 2, qA = tid & 3;
  int grA = m0 + rowA; if (grA >= NN) grA = NN - 1;
  const float* gA = x + (size_t)grA * F_IN + qA * 8;
  const int lofA = rowA * AST + qA * 16;
  const unsigned short* gB[4];
  int lofB[4];
#pragma unroll
  for (int ib = 0; ib < 4; ++ib) {
    int col = (tid >> 2) + 64 * ib, q = tid & 3;
    gB[ib]  = w1b + (size_t)col * F_IN + q * 8;
    lofB[ib] = ABYT + col * BST + q * 16;
  }

  f32x4 acc[4][4];
#pragma unroll
  for (int a = 0; a < 4; ++a)
#pragma unroll
    for (int b = 0; b < 4; ++b) acc[a][b] = (f32x4){0.f, 0.f, 0.f, 0.f};

  f32x4 pa0 = *(const f32x4*)(gA);
  f32x4 pa1 = *(const f32x4*)(gA + 4);
  bf16x8 rb[4];
#pragma unroll
  for (int ib = 0; ib < 4; ++ib) rb[ib] = *(const bf16x8*)(gB[ib]);
  {
    bf16x8 ab;
#pragma unroll
    for (int j = 0; j < 4; ++j) { ab[j] = (short)f2bf(pa0[j]); ab[j + 4] = (short)f2bf(pa1[j]); }
    *(bf16x8*)(lds + lofA) = ab;
#pragma unroll
    for (int ib = 0; ib < 4; ++ib) *(bf16x8*)(lds + lofB[ib]) = rb[ib];
  }
  __syncthreads();

  for (int c = 0; c < NCH; ++c) {
    char* buf = lds + (c & 1) * PBYT;
    if (c < NCH - 1) {
      pa0 = *(const f32x4*)(gA + (c + 1) * BKC);
      pa1 = *(const f32x4*)(gA + (c + 1) * BKC + 4);
#pragma unroll
      for (int ib = 0; ib < 4; ++ib) rb[ib] = *(const bf16x8*)(gB[ib] + (c + 1) * BKC);
    }
    bf16x8 af[4], bfr[4];
#pragma unroll
    for (int fm = 0; fm < 4; ++fm)
      af[fm] = *(const bf16x8*)(buf + (fm * 16 + lr) * AST + lk * 16);
#pragma unroll
    for (int fn = 0; fn < 4; ++fn)
      bfr[fn] = *(const bf16x8*)(buf + ABYT + (wv * 64 + fn * 16 + lr) * BST + lk * 16);
#pragma unroll
    for (int fm = 0; fm < 4; ++fm)
#pragma unroll
      for (int fn = 0; fn < 4; ++fn)
        acc[fm][fn] = __builtin_amdgcn_mfma_f32_16x16x32_bf16(af[fm], bfr[fn], acc[fm][fn],
                                                              0, 0, 0);
    if (c < NCH - 1) {
      char* nbuf = lds + ((c + 1) & 1) * PBYT;
      bf16x8 ab;
#pragma unroll
      for (int j = 0; j < 4; ++j) { ab[j] = (short)f2bf(pa0[j]); ab[j + 4] = (short)f2bf(pa1[j]); }
      *(bf16x8*)(nbuf + lofA) = ab;
#pragma unroll
      for (int ib = 0; ib < 4; ++ib) *(bf16x8*)(nbuf + lofB[ib]) = rb[ib];
    }
    __syncthreads();
  }

  // ---- epilogue 1: +b1, relu -> h1 overlay [64][264] bf16; w2 -> bf16 [16][264] ----
  unsigned short* h1p = (unsigned short*)lds;
  unsigned short* w2p = (unsigned short*)(lds + 64 * 264 * 2);
#pragma unroll
  for (int fn = 0; fn < 4; ++fn) {
    int col = wv * 64 + fn * 16 + lr;
    float bb = b1[col];
#pragma unroll
    for (int fm = 0; fm < 4; ++fm) {
#pragma unroll
      for (int r = 0; r < 4; ++r) {
        float v = acc[fm][fn][r] + bb;
        v = v > 0.f ? v : 0.f;
        h1p[(fm * 16 + lk * 4 + r) * 264 + col] = f2bf(v);
      }
    }
  }
  for (int i = tid; i < 16 * 256; i += 256) w2p[(i >> 8) * 264 + (i & 255)] = f2bf(w2[i]);
  __syncthreads();

  // ---- GEMM2 via MFMA: wave wv -> rows wv*16..+16, all 16 outputs ----
  f32x4 acc2 = (f32x4){0.f, 0.f, 0.f, 0.f};
#pragma unroll
  for (int ks = 0; ks < 8; ++ks) {
    bf16x8 a2 = *(const bf16x8*)&h1p[(wv * 16 + lr) * 264 + ks * 32 + lk * 8];
    bf16x8 b2f = *(const bf16x8*)&w2p[lr * 264 + ks * 32 + lk * 8];
    acc2 = __builtin_amdgcn_mfma_f32_16x16x32_bf16(a2, b2f, acc2, 0, 0, 0);
  }
  float bb2 = b2[lr];
#pragma unroll
  for (int r = 0; r < 4; ++r) {
    int row = m0 + wv * 16 + lk * 4 + r;
    if (row < NN) {
      float d = (float)(indeg[row] + 1);
      float di = rsqrtf(d);
      float v = (acc2[r] + bb2) * di;            // y0 value
      hterm[(size_t)row * F_OUT + lr] = 0.1f * v;
      float vo = __shfl_xor(v, 1, 64);           // partner feature, same row
      if ((lr & 1) == 0) {
        u32 pw = (u32)f2bf(v) | ((u32)f2bf(vo) << 16);
        y0[(size_t)row * 8 + (lr >> 1)] = pw;
      }
    }
  }
}

// ---- one PPR step, y packed bf16: 8 lanes per node, u32x4 gathers ----
// lane f2: es = f2>>1 (edge slot 0..3), hf = f2&1 (row half). 4 edges per round.
__global__ __launch_bounds__(256) void ppr_kernel(const int* __restrict__ node_off,
                                                  const int* __restrict__ indeg,
                                                  const int* __restrict__ csr_src,
                                                  const u32* __restrict__ yin,
                                                  const float* __restrict__ hterm,
                                                  u32* __restrict__ yout) {
  int t = blockIdx.x * 256 + threadIdx.x;
  int g = t >> 3, f2 = t & 7;
  if (g >= NN) return;
  const int lane = threadIdx.x & 63;
  const int gb = lane & 56;
  const int es = f2 >> 1, hf = f2 & 1;

  int deg = indeg[g], s0 = node_off[g];
  int pc = pad_cnt(deg);

  float al[4] = {0.f, 0.f, 0.f, 0.f};   // low features of words hf*4..hf*4+3
  float ah[4] = {0.f, 0.f, 0.f, 0.f};   // high features

  int sa = (pc > 0) ? csr_src[s0 + (f2 & 3)] : 0;
  for (int base = 0; base < pc; base += 4) {
    int nxt = (base + 4 < pc) ? base + 4 : base;
    int sa_n = csr_src[s0 + nxt + (f2 & 3)];
    int na = __shfl(sa, gb + es, 64);
    u32x4 v = *(const u32x4*)(yin + (size_t)na * 8 + hf * 4);
#pragma unroll
    for (int j = 0; j < 4; ++j) {
      al[j] += bflo(v[j]);
      ah[j] += bfhi(v[j]);
    }
    sa = sa_n;
  }
  // butterfly-reduce across the 4 es-lanes (bits 1,2 of lane id)
#pragma unroll
  for (int j = 0; j < 4; ++j) {
    al[j] += __shfl_xor(al[j], 2, 64);
    ah[j] += __shfl_xor(ah[j], 2, 64);
    al[j] += __shfl_xor(al[j], 4, 64);
    ah[j] += __shfl_xor(ah[j], 4, 64);
  }
  if (es == 0) {
    // add self row (half hf), scale, add hterm, pack, store 16B
    u32x4 sv = *(const u32x4*)(yin + (size_t)g * 8 + hf * 4);
    float ra = 0.9f * __builtin_amdgcn_rcpf((float)(deg + 1));
    f32x4 ht0 = *(const f32x4*)(hterm + (size_t)g * F_OUT + hf * 8);
    f32x4 ht1 = *(const f32x4*)(hterm + (size_t)g * F_OUT + hf * 8 + 4);
    u32x4 o;
#pragma unroll
    for (int j = 0; j < 4; ++j) {
      float lo = ra * (al[j] + bflo(sv[j]));
      float hi = ra * (ah[j] + bfhi(sv[j]));
      lo += (j < 2) ? ht0[2 * j] : ht1[2 * j - 4];
      hi += (j < 2) ? ht0[2 * j + 1] : ht1[2 * j - 3];
      o[j] = (u32)f2bf(lo) | ((u32)f2bf(hi) << 16);
    }
    *(u32x4*)(yout + (size_t)g * 8 + hf * 4) = o;
  }
}

// ---- output: z = sqrt(d) * y, unpack bf16 -> fp32 ----
__global__ __launch_bounds__(256) void out_kernel(const u32* __restrict__ y,
                                                  const int* __restrict__ indeg,
                                                  float* __restrict__ out) {
  int t = blockIdx.x * 256 + threadIdx.x;
  if (t >= NN * 8) return;
  float sd = sqrtf((float)(indeg[t >> 3] + 1));
  u32 w = y[t];
  f32x2 o = {bflo(w) * sd, bfhi(w) * sd};
  *(f32x2*)(out + (size_t)t * 2) = o;
}

extern "C" void kernel_launch(void* const* d_in, const int* in_sizes, int n_in,
                              void* d_out, int out_size, void* d_ws, size_t ws_size,
                              hipStream_t stream) {
  const float* x  = (const float*)d_in[0];
  const float* w1 = (const float*)d_in[1];
  const float* b1 = (const float*)d_in[2];
  const float* w2 = (const float*)d_in[3];
  const float* b2 = (const float*)d_in[4];
  const int*   ei = (const int*)d_in[5];

  char* p = (char*)d_ws;
  auto alloc = [&](size_t bytes) {
    char* r = p;
    p += (bytes + 255) & ~(size_t)255;
    return r;
  };
  float* hterm = (float*)alloc((size_t)NN * F_OUT * 4);
  u32* ya = (u32*)alloc((size_t)(NN + 1) * 8 * 4);
  u32* yb = (u32*)alloc((size_t)(NN + 1) * 8 * 4);
  unsigned short* w1b = (unsigned short*)alloc((size_t)F_HID * F_IN * 2);
  int* indeg = (int*)alloc(((size_t)2 * NN + 1) * 4);  // indeg | fillc | total
  int* fillc = indeg + NN;
  int* total = fillc + NN;
  int* node_off = (int*)alloc((size_t)NN * 4);
  int* csr_src  = (int*)alloc(((size_t)EE + (size_t)NN * 4 + 64) * 4);

  hipMemsetAsync(indeg, 0, ((size_t)2 * NN + 1) * 4, stream);

  convert_w1_kernel<<<(F_HID * F_IN + 255) / 256, 256, 0, stream>>>(w1, w1b);
  count_kernel<<<(EE + 255) / 256, 256, 0, stream>>>(ei, indeg);
  offsets_kernel<<<(NN + 255) / 256, 256, 0, stream>>>(indeg, node_off, total);
  fill_kernel<<<(EE + 255) / 256, 256, 0, stream>>>(ei, node_off, fillc, csr_src);
  pad_kernel<<<(NN + 255) / 256, 256, 0, stream>>>(indeg, node_off, csr_src, ya, yb);
  mlp_kernel<<<(NN + BM - 1) / BM, 256, 0, stream>>>(x, w1b, b1, w2, b2, indeg, hterm, ya);

  u32* yin = ya;
  u32* yout = yb;
  for (int k = 0; k < K_STEPS; ++k) {
    ppr_kernel<<<((size_t)NN * 8 + 255) / 256, 256, 0, stream>>>(node_off, indeg, csr_src,
                                                                 yin, hterm, yout);
    u32* tmp = yin; yin = yout; yout = tmp;
  }
  out_kernel<<<((size_t)NN * 8 + 255) / 256, 256, 0, stream>>>(yin, indeg, (float*)d_out);
}

// Round 10
// 458.365 us; speedup vs baseline: 2.4426x; 1.5182x over previous
//
#include <hip/hip_runtime.h>
#include <stdint.h>

#define F_IN 512
#define F_HID 256
#define F_OUT 16
#define K_STEPS 10
#define NN 100000
#define EE 3200000
#define NB 391                     // ceil(NN/256) buckets of 256 nodes
#define CHUNK 8192
#define NCHK ((EE + CHUNK - 1) / CHUNK)   // 391

typedef float f32x4 __attribute__((ext_vector_type(4)));
typedef float f32x2 __attribute__((ext_vector_type(2)));
typedef short bf16x8 __attribute__((ext_vector_type(8)));
typedef unsigned int u32;
typedef unsigned int u32x4 __attribute__((ext_vector_type(4)));

__device__ __forceinline__ unsigned short f2bf(float f) {
  unsigned u = __builtin_bit_cast(unsigned, f);
  u += 0x7FFFu + ((u >> 16) & 1u);   // RNE
  return (unsigned short)(u >> 16);
}
__device__ __forceinline__ float bflo(u32 w) { return __builtin_bit_cast(float, w << 16); }
__device__ __forceinline__ float bfhi(u32 w) { return __builtin_bit_cast(float, w & 0xffff0000u); }
__device__ __forceinline__ int pad_cnt(int deg) { return (deg + 3) & ~3; }

// ---- w1 -> bf16 ([256 hidden][512 k], k contiguous) ----
__global__ __launch_bounds__(256) void convert_w1_kernel(const float* __restrict__ w1,
                                                         unsigned short* __restrict__ w1b) {
  int i = blockIdx.x * 256 + threadIdx.x;
  if (i < F_HID * F_IN) w1b[i] = f2bf(w1[i]);
}

// ---- pass 1: per-bucket edge counts (LDS-aggregated) ----
__global__ __launch_bounds__(256) void bucket_count_kernel(const int* __restrict__ ei,
                                                           int* __restrict__ bucket_cnt) {
  __shared__ int cntL[512];
  const int tid = threadIdx.x;
  cntL[tid] = 0; cntL[tid + 256] = 0;
  __syncthreads();
  const int base = blockIdx.x * CHUNK;
  int n = EE - base; if (n > CHUNK) n = CHUNK;
  for (int k = tid; k < n; k += 256) {
    int c = ei[EE + base + k];
    atomicAdd(&cntL[c >> 8], 1);
  }
  __syncthreads();
  if (cntL[tid]) atomicAdd(&bucket_cnt[tid], cntL[tid]);
  if (tid + 256 < NB && cntL[tid + 256]) atomicAdd(&bucket_cnt[tid + 256], cntL[tid + 256]);
}

// ---- pass 2: allocate ebuf (exact) and csr (cnt+768 upper bound) regions ----
__global__ void alloc_kernel(const int* __restrict__ bucket_cnt,
                             int* __restrict__ ebuf_base, int* __restrict__ csr_base,
                             int* __restrict__ totals,
                             u32* __restrict__ ya, u32* __restrict__ yb) {
  int t = threadIdx.x;
  if (t < NB) {
    int c = bucket_cnt[t];
    ebuf_base[t] = atomicAdd(&totals[0], c);
    csr_base[t]  = atomicAdd(&totals[1], c + 768);
  }
  if (t >= 400 && t < 408) ya[(size_t)NN * 8 + (t - 400)] = 0;
  if (t >= 408 && t < 416) yb[(size_t)NN * 8 + (t - 408)] = 0;
}

// ---- pass 3: bin edges into bucket-major ebuf with run-contiguous flushes ----
__global__ __launch_bounds__(256) void scatter_kernel(const int* __restrict__ ei,
                                                      const int* __restrict__ ebuf_base,
                                                      int* __restrict__ ebuf_fill,
                                                      u32* __restrict__ ebuf) {
  __shared__ u32 sA[512], sB[512], cnt0[512], fillI[512], runb[512];
  __shared__ u32 staged[CHUNK], gaddrL[CHUNK];
  const int tid = threadIdx.x;
  const int base = blockIdx.x * CHUNK;
  int n = EE - base; if (n > CHUNK) n = CHUNK;

  sA[tid] = 0; sA[tid + 256] = 0;
  fillI[tid] = 0; fillI[tid + 256] = 0;
  __syncthreads();
  for (int k = tid; k < n; k += 256) {
    int c = ei[EE + base + k];
    atomicAdd(&sA[c >> 8], 1u);
  }
  __syncthreads();
  cnt0[tid] = sA[tid]; cnt0[tid + 256] = sA[tid + 256];
  __syncthreads();
  // inclusive scan over 512 (Hillis-Steele, ping-pong)
  u32* src = sA; u32* dst = sB;
  for (int off = 1; off < 512; off <<= 1) {
#pragma unroll
    for (int e = 0; e < 2; ++e) {
      int i = tid + e * 256;
      u32 v = src[i];
      if (i >= off) v += src[i - off];
      dst[i] = v;
    }
    __syncthreads();
    u32* tmp = src; src = dst; dst = tmp;
  }
  // src now holds inclusive scan; reserve global runs
#pragma unroll
  for (int e = 0; e < 2; ++e) {
    int b = tid + e * 256;
    if (b < NB && cnt0[b] > 0)
      runb[b] = (u32)ebuf_base[b] + (u32)atomicAdd(&ebuf_fill[b], (int)cnt0[b]);
  }
  __syncthreads();
  for (int k = tid; k < n; k += 256) {
    int r = ei[base + k];
    int c = ei[EE + base + k];
    int b = c >> 8;
    u32 excl = src[b] - cnt0[b];
    u32 slot = excl + atomicAdd(&fillI[b], 1u);
    staged[slot] = ((u32)r << 8) | (u32)(c & 255);
    gaddrL[slot] = runb[b] + (slot - excl);
  }
  __syncthreads();
  for (int s = tid; s < n; s += 256) ebuf[gaddrL[s]] = staged[s];
}

// ---- pass 4: per-bucket LDS counting sort -> coalesced final CSR + node_off/indeg ----
__global__ __launch_bounds__(256) void bucket_sort_kernel(const u32* __restrict__ ebuf,
                                                          const int* __restrict__ bucket_cnt,
                                                          const int* __restrict__ ebuf_base,
                                                          const int* __restrict__ csr_base,
                                                          int* __restrict__ node_off,
                                                          int* __restrict__ indeg,
                                                          int* __restrict__ csr_src) {
  __shared__ int degL[256], exclL[256], scT[256], fillL[256];
  __shared__ u32 sorted[10240];
  const int t = threadIdx.x;
  const int b = blockIdx.x;
  const int n0 = b << 8;
  const int nInB = (NN - n0) < 256 ? (NN - n0) : 256;
  const int cnt = bucket_cnt[b];
  const int ebase = ebuf_base[b];
  const int cbase = csr_base[b];

  degL[t] = 0;
  for (int j = t; j < 10240; j += 256) sorted[j] = NN;   // sentinel prefill
  __syncthreads();
  for (int j = t; j < cnt; j += 256) atomicAdd(&degL[(int)(ebuf[ebase + j] & 255u)], 1);
  __syncthreads();
  int deg = degL[t];
  int pcnt = (deg + 3) & ~3;
  scT[t] = pcnt;
  __syncthreads();
  for (int off = 1; off < 256; off <<= 1) {
    int v = (t >= off) ? scT[t - off] : 0;
    __syncthreads();
    scT[t] += v;
    __syncthreads();
  }
  int excl = scT[t] - pcnt;
  exclL[t] = excl;
  fillL[t] = 0;
  int total = scT[255];
  if (t < nInB) {
    node_off[n0 + t] = cbase + excl;
    indeg[n0 + t] = deg;
  }
  __syncthreads();
  for (int j = t; j < cnt; j += 256) {
    u32 e = ebuf[ebase + j];
    int nl = (int)(e & 255u);
    int pos = exclL[nl] + atomicAdd(&fillL[nl], 1);
    sorted[pos] = e >> 8;
  }
  __syncthreads();
  for (int j = t; j < total; j += 256) csr_src[cbase + j] = (int)sorted[j];
}

// ---- MFMA MLP (x-conversion fused into staging): 64x256 tile, 4 waves x (64x64) ----
#define BM 64
#define BKC 32
#define NCH (F_IN / BKC)
#define AST 80
#define BST 80
#define ABYT (BM * AST)
#define BBYT (F_HID * BST)
#define PBYT (ABYT + BBYT)
__global__ __launch_bounds__(256) void mlp_kernel(const float* __restrict__ x,
                                                  const unsigned short* __restrict__ w1b,
                                                  const float* __restrict__ b1,
                                                  const float* __restrict__ w2,
                                                  const float* __restrict__ b2,
                                                  const int* __restrict__ indeg,
                                                  float* __restrict__ hterm,
                                                  u32* __restrict__ y0) {
  __shared__ char lds[2 * PBYT];
  const int tid = threadIdx.x;
  const int wv = tid >> 6, l = tid & 63;
  const int lr = l & 15, lk = l >> 4;
  const int m0 = blockIdx.x * BM;

  const int rowA = tid >> 2, qA = tid & 3;
  int grA = m0 + rowA; if (grA >= NN) grA = NN - 1;
  const float* gA = x + (size_t)grA * F_IN + qA * 8;
  const int lofA = rowA * AST + qA * 16;
  const unsigned short* gB[4];
  int lofB[4];
#pragma unroll
  for (int ib = 0; ib < 4; ++ib) {
    int col = (tid >> 2) + 64 * ib, q = tid & 3;
    gB[ib]  = w1b + (size_t)col * F_IN + q * 8;
    lofB[ib] = ABYT + col * BST + q * 16;
  }

  f32x4 acc[4][4];
#pragma unroll
  for (int a = 0; a < 4; ++a)
#pragma unroll
    for (int b = 0; b < 4; ++b) acc[a][b] = (f32x4){0.f, 0.f, 0.f, 0.f};

  f32x4 pa0 = *(const f32x4*)(gA);
  f32x4 pa1 = *(const f32x4*)(gA + 4);
  bf16x8 rb[4];
#pragma unroll
  for (int ib = 0; ib < 4; ++ib) rb[ib] = *(const bf16x8*)(gB[ib]);
  {
    bf16x8 ab;
#pragma unroll
    for (int j = 0; j < 4; ++j) { ab[j] = (short)f2bf(pa0[j]); ab[j + 4] = (short)f2bf(pa1[j]); }
    *(bf16x8*)(lds + lofA) = ab;
#pragma unroll
    for (int ib = 0; ib < 4; ++ib) *(bf16x8*)(lds + lofB[ib]) = rb[ib];
  }
  __syncthreads();

  for (int c = 0; c < NCH; ++c) {
    char* buf = lds + (c & 1) * PBYT;
    if (c < NCH - 1) {
      pa0 = *(const f32x4*)(gA + (c + 1) * BKC);
      pa1 = *(const f32x4*)(gA + (c + 1) * BKC + 4);
#pragma unroll
      for (int ib = 0; ib < 4; ++ib) rb[ib] = *(const bf16x8*)(gB[ib] + (c + 1) * BKC);
    }
    bf16x8 af[4], bfr[4];
#pragma unroll
    for (int fm = 0; fm < 4; ++fm)
      af[fm] = *(const bf16x8*)(buf + (fm * 16 + lr) * AST + lk * 16);
#pragma unroll
    for (int fn = 0; fn < 4; ++fn)
      bfr[fn] = *(const bf16x8*)(buf + ABYT + (wv * 64 + fn * 16 + lr) * BST + lk * 16);
#pragma unroll
    for (int fm = 0; fm < 4; ++fm)
#pragma unroll
      for (int fn = 0; fn < 4; ++fn)
        acc[fm][fn] = __builtin_amdgcn_mfma_f32_16x16x32_bf16(af[fm], bfr[fn], acc[fm][fn],
                                                              0, 0, 0);
    if (c < NCH - 1) {
      char* nbuf = lds + ((c + 1) & 1) * PBYT;
      bf16x8 ab;
#pragma unroll
      for (int j = 0; j < 4; ++j) { ab[j] = (short)f2bf(pa0[j]); ab[j + 4] = (short)f2bf(pa1[j]); }
      *(bf16x8*)(nbuf + lofA) = ab;
#pragma unroll
      for (int ib = 0; ib < 4; ++ib) *(bf16x8*)(nbuf + lofB[ib]) = rb[ib];
    }
    __syncthreads();
  }

  unsigned short* h1p = (unsigned short*)lds;
  unsigned short* w2p = (unsigned short*)(lds + 64 * 264 * 2);
#pragma unroll
  for (int fn = 0; fn < 4; ++fn) {
    int col = wv * 64 + fn * 16 + lr;
    float bb = b1[col];
#pragma unroll
    for (int fm = 0; fm < 4; ++fm) {
#pragma unroll
      for (int r = 0; r < 4; ++r) {
        float v = acc[fm][fn][r] + bb;
        v = v > 0.f ? v : 0.f;
        h1p[(fm * 16 + lk * 4 + r) * 264 + col] = f2bf(v);
      }
    }
  }
  for (int i = tid; i < 16 * 256; i += 256) w2p[(i >> 8) * 264 + (i & 255)] = f2bf(w2[i]);
  __syncthreads();

  f32x4 acc2 = (f32x4){0.f, 0.f, 0.f, 0.f};
#pragma unroll
  for (int ks = 0; ks < 8; ++ks) {
    bf16x8 a2 = *(const bf16x8*)&h1p[(wv * 16 + lr) * 264 + ks * 32 + lk * 8];
    bf16x8 b2f = *(const bf16x8*)&w2p[lr * 264 + ks * 32 + lk * 8];
    acc2 = __builtin_amdgcn_mfma_f32_16x16x32_bf16(a2, b2f, acc2, 0, 0, 0);
  }
  float bb2 = b2[lr];
#pragma unroll
  for (int r = 0; r < 4; ++r) {
    int row = m0 + wv * 16 + lk * 4 + r;
    if (row < NN) {
      float d = (float)(indeg[row] + 1);
      float di = rsqrtf(d);
      float v = (acc2[r] + bb2) * di;
      hterm[(size_t)row * F_OUT + lr] = 0.1f * v;
      float vo = __shfl_xor(v, 1, 64);
      if ((lr & 1) == 0) {
        u32 pw = (u32)f2bf(v) | ((u32)f2bf(vo) << 16);
        y0[(size_t)row * 8 + (lr >> 1)] = pw;
      }
    }
  }
}

// ---- one PPR step, y packed bf16: 8 lanes per node, u32x4 gathers ----
__global__ __launch_bounds__(256) void ppr_kernel(const int* __restrict__ node_off,
                                                  const int* __restrict__ indeg,
                                                  const int* __restrict__ csr_src,
                                                  const u32* __restrict__ yin,
                                                  const float* __restrict__ hterm,
                                                  u32* __restrict__ yout) {
  int t = blockIdx.x * 256 + threadIdx.x;
  int g = t >> 3, f2 = t & 7;
  if (g >= NN) return;
  const int lane = threadIdx.x & 63;
  const int gb = lane & 56;
  const int es = f2 >> 1, hf = f2 & 1;

  int deg = indeg[g], s0 = node_off[g];
  int pc = pad_cnt(deg);

  float al[4] = {0.f, 0.f, 0.f, 0.f};
  float ah[4] = {0.f, 0.f, 0.f, 0.f};

  int sa = (pc > 0) ? csr_src[s0 + (f2 & 3)] : 0;
  for (int base = 0; base < pc; base += 4) {
    int nxt = (base + 4 < pc) ? base + 4 : base;
    int sa_n = csr_src[s0 + nxt + (f2 & 3)];
    int na = __shfl(sa, gb + es, 64);
    u32x4 v = *(const u32x4*)(yin + (size_t)na * 8 + hf * 4);
#pragma unroll
    for (int j = 0; j < 4; ++j) {
      al[j] += bflo(v[j]);
      ah[j] += bfhi(v[j]);
    }
    sa = sa_n;
  }
#pragma unroll
  for (int j = 0; j < 4; ++j) {
    al[j] += __shfl_xor(al[j], 2, 64);
    ah[j] += __shfl_xor(ah[j], 2, 64);
    al[j] += __shfl_xor(al[j], 4, 64);
    ah[j] += __shfl_xor(ah[j], 4, 64);
  }
  if (es == 0) {
    u32x4 sv = *(const u32x4*)(yin + (size_t)g * 8 + hf * 4);
    float ra = 0.9f * __builtin_amdgcn_rcpf((float)(deg + 1));
    f32x4 ht0 = *(const f32x4*)(hterm + (size_t)g * F_OUT + hf * 8);
    f32x4 ht1 = *(const f32x4*)(hterm + (size_t)g * F_OUT + hf * 8 + 4);
    u32x4 o;
#pragma unroll
    for (int j = 0; j < 4; ++j) {
      float lo = ra * (al[j] + bflo(sv[j]));
      float hi = ra * (ah[j] + bfhi(sv[j]));
      lo += (j < 2) ? ht0[2 * j] : ht1[2 * j - 4];
      hi += (j < 2) ? ht0[2 * j + 1] : ht1[2 * j - 3];
      o[j] = (u32)f2bf(lo) | ((u32)f2bf(hi) << 16);
    }
    *(u32x4*)(yout + (size_t)g * 8 + hf * 4) = o;
  }
}

// ---- output: z = sqrt(d) * y, unpack bf16 -> fp32 ----
__global__ __launch_bounds__(256) void out_kernel(const u32* __restrict__ y,
                                                  const int* __restrict__ indeg,
                                                  float* __restrict__ out) {
  int t = blockIdx.x * 256 + threadIdx.x;
  if (t >= NN * 8) return;
  float sd = sqrtf((float)(indeg[t >> 3] + 1));
  u32 w = y[t];
  f32x2 o = {bflo(w) * sd, bfhi(w) * sd};
  *(f32x2*)(out + (size_t)t * 2) = o;
}

extern "C" void kernel_launch(void* const* d_in, const int* in_sizes, int n_in,
                              void* d_out, int out_size, void* d_ws, size_t ws_size,
                              hipStream_t stream) {
  const float* x  = (const float*)d_in[0];
  const float* w1 = (const float*)d_in[1];
  const float* b1 = (const float*)d_in[2];
  const float* w2 = (const float*)d_in[3];
  const float* b2 = (const float*)d_in[4];
  const int*   ei = (const int*)d_in[5];

  char* p = (char*)d_ws;
  auto alloc = [&](size_t bytes) {
    char* r = p;
    p += (bytes + 255) & ~(size_t)255;
    return r;
  };
  float* hterm = (float*)alloc((size_t)NN * F_OUT * 4);
  u32* ya = (u32*)alloc((size_t)(NN + 1) * 8 * 4);
  u32* yb = (u32*)alloc((size_t)(NN + 1) * 8 * 4);
  unsigned short* w1b = (unsigned short*)alloc((size_t)F_HID * F_IN * 2);
  int* aux = (int*)alloc(((size_t)2 * NB + 2) * 4);    // bucket_cnt | ebuf_fill | totals[2]
  int* bucket_cnt = aux;
  int* ebuf_fill  = aux + NB;
  int* totals     = aux + 2 * NB;
  int* ebuf_base = (int*)alloc((size_t)NB * 4);
  int* csr_base  = (int*)alloc((size_t)NB * 4);
  int* node_off  = (int*)alloc((size_t)NN * 4);
  int* indeg     = (int*)alloc((size_t)NN * 4);
  u32* ebuf      = (u32*)alloc((size_t)EE * 4);
  int* csr_src   = (int*)alloc(((size_t)EE + (size_t)NB * 768) * 4);

  hipMemsetAsync(aux, 0, ((size_t)2 * NB + 2) * 4, stream);

  convert_w1_kernel<<<(F_HID * F_IN + 255) / 256, 256, 0, stream>>>(w1, w1b);
  bucket_count_kernel<<<NCHK, 256, 0, stream>>>(ei, bucket_cnt);
  alloc_kernel<<<1, 512, 0, stream>>>(bucket_cnt, ebuf_base, csr_base, totals, ya, yb);
  scatter_kernel<<<NCHK, 256, 0, stream>>>(ei, ebuf_base, ebuf_fill, ebuf);
  bucket_sort_kernel<<<NB, 256, 0, stream>>>(ebuf, bucket_cnt, ebuf_base, csr_base,
                                             node_off, indeg, csr_src);
  mlp_kernel<<<(NN + BM - 1) / BM, 256, 0, stream>>>(x, w1b, b1, w2, b2, indeg, hterm, ya);

  u32* yin = ya;
  u32* yout = yb;
  for (int k = 0; k < K_STEPS; ++k) {
    ppr_kernel<<<((size_t)NN * 8 + 255) / 256, 256, 0, stream>>>(node_off, indeg, csr_src,
                                                                 yin, hterm, yout);
    u32* tmp = yin; yin = yout; yout = tmp;
  }
  out_kernel<<<((size_t)NN * 8 + 255) / 256, 256, 0, stream>>>(yin, indeg, (float*)d_out);
}

// Round 11
// 443.426 us; speedup vs baseline: 2.5249x; 1.0337x over previous
//
#include <hip/hip_runtime.h>
#include <stdint.h>

#define F_IN 512
#define F_HID 256
#define F_OUT 16
#define K_STEPS 10
#define NN 100000
#define EE 3200000
#define NB 391                     // ceil(NN/256) buckets of 256 nodes
#define CHUNK 8192
#define NCHK ((EE + CHUNK - 1) / CHUNK)   // 391

typedef float f32x4 __attribute__((ext_vector_type(4)));
typedef float f32x2 __attribute__((ext_vector_type(2)));
typedef short bf16x8 __attribute__((ext_vector_type(8)));
typedef unsigned int u32;
typedef unsigned int u32x4 __attribute__((ext_vector_type(4)));

__device__ __forceinline__ unsigned short f2bf(float f) {
  unsigned u = __builtin_bit_cast(unsigned, f);
  u += 0x7FFFu + ((u >> 16) & 1u);   // RNE
  return (unsigned short)(u >> 16);
}
__device__ __forceinline__ float bflo(u32 w) { return __builtin_bit_cast(float, w << 16); }
__device__ __forceinline__ float bfhi(u32 w) { return __builtin_bit_cast(float, w & 0xffff0000u); }

// ---- w1 -> bf16 ([256 hidden][512 k], k contiguous) ----
__global__ __launch_bounds__(256) void convert_w1_kernel(const float* __restrict__ w1,
                                                         unsigned short* __restrict__ w1b) {
  int i = blockIdx.x * 256 + threadIdx.x;
  if (i < F_HID * F_IN) w1b[i] = f2bf(w1[i]);
}

// ---- pass 1: per-bucket edge counts (LDS-aggregated) ----
__global__ __launch_bounds__(256) void bucket_count_kernel(const int* __restrict__ ei,
                                                           int* __restrict__ bucket_cnt) {
  __shared__ int cntL[512];
  const int tid = threadIdx.x;
  cntL[tid] = 0; cntL[tid + 256] = 0;
  __syncthreads();
  const int base = blockIdx.x * CHUNK;
  int n = EE - base; if (n > CHUNK) n = CHUNK;
  for (int k = tid; k < n; k += 256) {
    int c = ei[EE + base + k];
    atomicAdd(&cntL[c >> 8], 1);
  }
  __syncthreads();
  if (cntL[tid]) atomicAdd(&bucket_cnt[tid], cntL[tid]);
  if (tid + 256 < NB && cntL[tid + 256]) atomicAdd(&bucket_cnt[tid + 256], cntL[tid + 256]);
}

// ---- pass 2: allocate ebuf (exact) and csr (pad8 + slack) regions; zero sentinel rows ----
__global__ void alloc_kernel(const int* __restrict__ bucket_cnt,
                             int* __restrict__ ebuf_base, int* __restrict__ csr_base,
                             int* __restrict__ totals,
                             u32* __restrict__ ya, u32* __restrict__ yb) {
  int t = threadIdx.x;
  if (t < NB) {
    int c = bucket_cnt[t];
    ebuf_base[t] = atomicAdd(&totals[0], c);
    csr_base[t]  = atomicAdd(&totals[1], ((c + 7) & ~7) + 2048);
  }
  if (t >= 400 && t < 408) ya[(size_t)NN * 8 + (t - 400)] = 0;
  if (t >= 408 && t < 416) yb[(size_t)NN * 8 + (t - 408)] = 0;
}

// ---- pass 3: bin edges into bucket-major ebuf with run-contiguous flushes ----
__global__ __launch_bounds__(256) void scatter_kernel(const int* __restrict__ ei,
                                                      const int* __restrict__ ebuf_base,
                                                      int* __restrict__ ebuf_fill,
                                                      u32* __restrict__ ebuf) {
  __shared__ u32 sA[512], sB[512], cnt0[512], fillI[512], runb[512];
  __shared__ u32 staged[CHUNK], gaddrL[CHUNK];
  const int tid = threadIdx.x;
  const int base = blockIdx.x * CHUNK;
  int n = EE - base; if (n > CHUNK) n = CHUNK;

  sA[tid] = 0; sA[tid + 256] = 0;
  fillI[tid] = 0; fillI[tid + 256] = 0;
  __syncthreads();
  for (int k = tid; k < n; k += 256) {
    int c = ei[EE + base + k];
    atomicAdd(&sA[c >> 8], 1u);
  }
  __syncthreads();
  cnt0[tid] = sA[tid]; cnt0[tid + 256] = sA[tid + 256];
  __syncthreads();
  u32* src = sA; u32* dst = sB;
  for (int off = 1; off < 512; off <<= 1) {
#pragma unroll
    for (int e = 0; e < 2; ++e) {
      int i = tid + e * 256;
      u32 v = src[i];
      if (i >= off) v += src[i - off];
      dst[i] = v;
    }
    __syncthreads();
    u32* tmp = src; src = dst; dst = tmp;
  }
#pragma unroll
  for (int e = 0; e < 2; ++e) {
    int b = tid + e * 256;
    if (b < NB && cnt0[b] > 0)
      runb[b] = (u32)ebuf_base[b] + (u32)atomicAdd(&ebuf_fill[b], (int)cnt0[b]);
  }
  __syncthreads();
  for (int k = tid; k < n; k += 256) {
    int r = ei[base + k];
    int c = ei[EE + base + k];
    int b = c >> 8;
    u32 excl = src[b] - cnt0[b];
    u32 slot = excl + atomicAdd(&fillI[b], 1u);
    staged[slot] = ((u32)r << 8) | (u32)(c & 255);
    gaddrL[slot] = runb[b] + (slot - excl);
  }
  __syncthreads();
  for (int s = tid; s < n; s += 256) ebuf[gaddrL[s]] = staged[s];
}

// ---- pass 4: per-bucket counting sort -> coalesced pad8-CSR + node_off/indeg + perm ----
__global__ __launch_bounds__(256) void bucket_sort_kernel(const u32* __restrict__ ebuf,
                                                          const int* __restrict__ bucket_cnt,
                                                          const int* __restrict__ ebuf_base,
                                                          const int* __restrict__ csr_base,
                                                          int* __restrict__ node_off,
                                                          int* __restrict__ indeg,
                                                          int* __restrict__ csr_src,
                                                          int* __restrict__ perm) {
  __shared__ int degL[256], exclL[256], scT[256], fillL[256];
  __shared__ int binc[64], bino[64], binf[64];
  __shared__ u32 sorted[12288];
  const int t = threadIdx.x;
  const int b = blockIdx.x;
  const int n0 = b << 8;
  const int nInB = (NN - n0) < 256 ? (NN - n0) : 256;
  const int cnt = bucket_cnt[b];
  const int ebase = ebuf_base[b];
  const int cbase = csr_base[b];

  degL[t] = 0;
  if (t < 64) { binc[t] = 0; binf[t] = 0; }
  for (int j = t; j < 12288; j += 256) sorted[j] = NN;   // sentinel prefill
  __syncthreads();
  for (int j = t; j < cnt; j += 256) atomicAdd(&degL[(int)(ebuf[ebase + j] & 255u)], 1);
  __syncthreads();
  int deg = degL[t];
  int pcnt = (deg + 7) & ~7;                             // pad to 8
  scT[t] = pcnt;
  __syncthreads();
  for (int off = 1; off < 256; off <<= 1) {
    int v = (t >= off) ? scT[t - off] : 0;
    __syncthreads();
    scT[t] += v;
    __syncthreads();
  }
  int excl = scT[t] - pcnt;
  exclL[t] = excl;
  fillL[t] = 0;
  int total = scT[255];
  if (t < nInB) {
    node_off[n0 + t] = cbase + excl;
    indeg[n0 + t] = deg;
  }
  // degree-sorted permutation (counting sort by pcnt/8, order within bin arbitrary)
  int key = pcnt >> 3; if (key > 63) key = 63;
  if (t < nInB) atomicAdd(&binc[key], 1);
  __syncthreads();
  if (t == 0) { int s = 0; for (int k2 = 0; k2 < 64; ++k2) { bino[k2] = s; s += binc[k2]; } }
  __syncthreads();
  if (t < nInB) {
    int rank = bino[key] + atomicAdd(&binf[key], 1);
    perm[n0 + rank] = n0 + t;
  }
  for (int j = t; j < cnt; j += 256) {
    u32 e = ebuf[ebase + j];
    int nl = (int)(e & 255u);
    int pos = exclL[nl] + atomicAdd(&fillL[nl], 1);
    sorted[pos] = e >> 8;
  }
  __syncthreads();
  for (int j = t; j < total; j += 256) csr_src[cbase + j] = (int)sorted[j];
}

// ---- MFMA MLP: 64x256 tile, 4 waves x (64x64); writes y0 + hterm both packed bf16 ----
#define BM 64
#define BKC 32
#define NCH (F_IN / BKC)
#define AST 80
#define BST 80
#define ABYT (BM * AST)
#define BBYT (F_HID * BST)
#define PBYT (ABYT + BBYT)
__global__ __launch_bounds__(256) void mlp_kernel(const float* __restrict__ x,
                                                  const unsigned short* __restrict__ w1b,
                                                  const float* __restrict__ b1,
                                                  const float* __restrict__ w2,
                                                  const float* __restrict__ b2,
                                                  const int* __restrict__ indeg,
                                                  u32* __restrict__ htermp,
                                                  u32* __restrict__ y0) {
  __shared__ char lds[2 * PBYT];
  const int tid = threadIdx.x;
  const int wv = tid >> 6, l = tid & 63;
  const int lr = l & 15, lk = l >> 4;
  const int m0 = blockIdx.x * BM;

  const int rowA = tid >> 2, qA = tid & 3;
  int grA = m0 + rowA; if (grA >= NN) grA = NN - 1;
  const float* gA = x + (size_t)grA * F_IN + qA * 8;
  const int lofA = rowA * AST + qA * 16;
  const unsigned short* gB[4];
  int lofB[4];
#pragma unroll
  for (int ib = 0; ib < 4; ++ib) {
    int col = (tid >> 2) + 64 * ib, q = tid & 3;
    gB[ib]  = w1b + (size_t)col * F_IN + q * 8;
    lofB[ib] = ABYT + col * BST + q * 16;
  }

  f32x4 acc[4][4];
#pragma unroll
  for (int a = 0; a < 4; ++a)
#pragma unroll
    for (int b = 0; b < 4; ++b) acc[a][b] = (f32x4){0.f, 0.f, 0.f, 0.f};

  f32x4 pa0 = *(const f32x4*)(gA);
  f32x4 pa1 = *(const f32x4*)(gA + 4);
  bf16x8 rb[4];
#pragma unroll
  for (int ib = 0; ib < 4; ++ib) rb[ib] = *(const bf16x8*)(gB[ib]);
  {
    bf16x8 ab;
#pragma unroll
    for (int j = 0; j < 4; ++j) { ab[j] = (short)f2bf(pa0[j]); ab[j + 4] = (short)f2bf(pa1[j]); }
    *(bf16x8*)(lds + lofA) = ab;
#pragma unroll
    for (int ib = 0; ib < 4; ++ib) *(bf16x8*)(lds + lofB[ib]) = rb[ib];
  }
  __syncthreads();

  for (int c = 0; c < NCH; ++c) {
    char* buf = lds + (c & 1) * PBYT;
    if (c < NCH - 1) {
      pa0 = *(const f32x4*)(gA + (c + 1) * BKC);
      pa1 = *(const f32x4*)(gA + (c + 1) * BKC + 4);
#pragma unroll
      for (int ib = 0; ib < 4; ++ib) rb[ib] = *(const bf16x8*)(gB[ib] + (c + 1) * BKC);
    }
    bf16x8 af[4], bfr[4];
#pragma unroll
    for (int fm = 0; fm < 4; ++fm)
      af[fm] = *(const bf16x8*)(buf + (fm * 16 + lr) * AST + lk * 16);
#pragma unroll
    for (int fn = 0; fn < 4; ++fn)
      bfr[fn] = *(const bf16x8*)(buf + ABYT + (wv * 64 + fn * 16 + lr) * BST + lk * 16);
#pragma unroll
    for (int fm = 0; fm < 4; ++fm)
#pragma unroll
      for (int fn = 0; fn < 4; ++fn)
        acc[fm][fn] = __builtin_amdgcn_mfma_f32_16x16x32_bf16(af[fm], bfr[fn], acc[fm][fn],
                                                              0, 0, 0);
    if (c < NCH - 1) {
      char* nbuf = lds + ((c + 1) & 1) * PBYT;
      bf16x8 ab;
#pragma unroll
      for (int j = 0; j < 4; ++j) { ab[j] = (short)f2bf(pa0[j]); ab[j + 4] = (short)f2bf(pa1[j]); }
      *(bf16x8*)(nbuf + lofA) = ab;
#pragma unroll
      for (int ib = 0; ib < 4; ++ib) *(bf16x8*)(nbuf + lofB[ib]) = rb[ib];
    }
    __syncthreads();
  }

  unsigned short* h1p = (unsigned short*)lds;
  unsigned short* w2p = (unsigned short*)(lds + 64 * 264 * 2);
#pragma unroll
  for (int fn = 0; fn < 4; ++fn) {
    int col = wv * 64 + fn * 16 + lr;
    float bb = b1[col];
#pragma unroll
    for (int fm = 0; fm < 4; ++fm) {
#pragma unroll
      for (int r = 0; r < 4; ++r) {
        float v = acc[fm][fn][r] + bb;
        v = v > 0.f ? v : 0.f;
        h1p[(fm * 16 + lk * 4 + r) * 264 + col] = f2bf(v);
      }
    }
  }
  for (int i = tid; i < 16 * 256; i += 256) w2p[(i >> 8) * 264 + (i & 255)] = f2bf(w2[i]);
  __syncthreads();

  f32x4 acc2 = (f32x4){0.f, 0.f, 0.f, 0.f};
#pragma unroll
  for (int ks = 0; ks < 8; ++ks) {
    bf16x8 a2 = *(const bf16x8*)&h1p[(wv * 16 + lr) * 264 + ks * 32 + lk * 8];
    bf16x8 b2f = *(const bf16x8*)&w2p[lr * 264 + ks * 32 + lk * 8];
    acc2 = __builtin_amdgcn_mfma_f32_16x16x32_bf16(a2, b2f, acc2, 0, 0, 0);
  }
  float bb2 = b2[lr];
#pragma unroll
  for (int r = 0; r < 4; ++r) {
    int row = m0 + wv * 16 + lk * 4 + r;
    if (row < NN) {
      float d = (float)(indeg[row] + 1);
      float di = rsqrtf(d);
      float v = (acc2[r] + bb2) * di;            // y0 value for feature lr
      float vo = __shfl_xor(v, 1, 64);           // partner feature, same row
      if ((lr & 1) == 0) {
        y0[(size_t)row * 8 + (lr >> 1)] = (u32)f2bf(v) | ((u32)f2bf(vo) << 16);
        htermp[(size_t)row * 8 + (lr >> 1)] =
            (u32)f2bf(0.1f * v) | ((u32)f2bf(0.1f * vo) << 16);
      }
    }
  }
}

// ---- one PPR step: 4 lanes/node (eo=edge-slot, hf=row half); no per-edge shuffles ----
__global__ __launch_bounds__(256) void ppr_kernel(const int* __restrict__ node_off,
                                                  const int* __restrict__ indeg,
                                                  const int* __restrict__ perm,
                                                  const int* __restrict__ csr_src,
                                                  const u32* __restrict__ yin,
                                                  const u32* __restrict__ htermp,
                                                  u32* __restrict__ yout) {
  int t = blockIdx.x * 256 + threadIdx.x;
  int i = t >> 2;
  if (i >= NN) return;
  const int sub = t & 3, eo = sub >> 1, hf = sub & 1;
  const int g = perm[i];
  const int deg = indeg[g], s0 = node_off[g];
  const int nblk = ((deg + 7) & ~7) >> 3;         // 8-edge super-blocks

  float al[4] = {0.f, 0.f, 0.f, 0.f};
  float ah[4] = {0.f, 0.f, 0.f, 0.f};

  const u32* cp = (const u32*)csr_src + s0 + eo * 4;
  u32x4 sidx;
  if (nblk > 0) sidx = *(const u32x4*)cp;
  for (int b = 0; b < nblk; ++b) {
    u32x4 snxt;
    if (b + 1 < nblk) snxt = *(const u32x4*)(cp + (size_t)(b + 1) * 8);
#pragma unroll
    for (int j = 0; j < 4; ++j) {
      u32x4 v = *(const u32x4*)(yin + (size_t)sidx[j] * 8 + hf * 4);
      al[0] += bflo(v[0]); ah[0] += bfhi(v[0]);
      al[1] += bflo(v[1]); ah[1] += bfhi(v[1]);
      al[2] += bflo(v[2]); ah[2] += bfhi(v[2]);
      al[3] += bflo(v[3]); ah[3] += bfhi(v[3]);
    }
    sidx = snxt;
  }
  // combine the two eo lanes (lane bit 1)
#pragma unroll
  for (int j = 0; j < 4; ++j) {
    al[j] += __shfl_xor(al[j], 2, 64);
    ah[j] += __shfl_xor(ah[j], 2, 64);
  }
  if (eo == 0) {
    u32x4 sv = *(const u32x4*)(yin + (size_t)g * 8 + hf * 4);
    u32x4 hp = *(const u32x4*)(htermp + (size_t)g * 8 + hf * 4);
    float ra = 0.9f * __builtin_amdgcn_rcpf((float)(deg + 1));
    u32x4 o;
#pragma unroll
    for (int j = 0; j < 4; ++j) {
      float lo = ra * (al[j] + bflo(sv[j])) + bflo(hp[j]);
      float hi = ra * (ah[j] + bfhi(sv[j])) + bfhi(hp[j]);
      o[j] = (u32)f2bf(lo) | ((u32)f2bf(hi) << 16);
    }
    *(u32x4*)(yout + (size_t)g * 8 + hf * 4) = o;
  }
}

// ---- output: z = sqrt(d) * y, unpack bf16 -> fp32 ----
__global__ __launch_bounds__(256) void out_kernel(const u32* __restrict__ y,
                                                  const int* __restrict__ indeg,
                                                  float* __restrict__ out) {
  int t = blockIdx.x * 256 + threadIdx.x;
  if (t >= NN * 8) return;
  float sd = sqrtf((float)(indeg[t >> 3] + 1));
  u32 w = y[t];
  f32x2 o = {bflo(w) * sd, bfhi(w) * sd};
  *(f32x2*)(out + (size_t)t * 2) = o;
}

extern "C" void kernel_launch(void* const* d_in, const int* in_sizes, int n_in,
                              void* d_out, int out_size, void* d_ws, size_t ws_size,
                              hipStream_t stream) {
  const float* x  = (const float*)d_in[0];
  const float* w1 = (const float*)d_in[1];
  const float* b1 = (const float*)d_in[2];
  const float* w2 = (const float*)d_in[3];
  const float* b2 = (const float*)d_in[4];
  const int*   ei = (const int*)d_in[5];

  char* p = (char*)d_ws;
  auto alloc = [&](size_t bytes) {
    char* r = p;
    p += (bytes + 255) & ~(size_t)255;
    return r;
  };
  u32* htermp = (u32*)alloc((size_t)NN * 8 * 4);
  u32* ya = (u32*)alloc((size_t)(NN + 1) * 8 * 4);
  u32* yb = (u32*)alloc((size_t)(NN + 1) * 8 * 4);
  unsigned short* w1b = (unsigned short*)alloc((size_t)F_HID * F_IN * 2);
  int* aux = (int*)alloc(((size_t)2 * NB + 2) * 4);    // bucket_cnt | ebuf_fill | totals[2]
  int* bucket_cnt = aux;
  int* ebuf_fill  = aux + NB;
  int* totals     = aux + 2 * NB;
  int* ebuf_base = (int*)alloc((size_t)NB * 4);
  int* csr_base  = (int*)alloc((size_t)NB * 4);
  int* node_off  = (int*)alloc((size_t)NN * 4);
  int* indeg     = (int*)alloc((size_t)NN * 4);
  int* perm      = (int*)alloc((size_t)NN * 4);
  u32* ebuf      = (u32*)alloc((size_t)EE * 4);
  int* csr_src   = (int*)alloc(((size_t)EE + (size_t)NB * 2048 + 64) * 4);

  hipMemsetAsync(aux, 0, ((size_t)2 * NB + 2) * 4, stream);

  convert_w1_kernel<<<(F_HID * F_IN + 255) / 256, 256, 0, stream>>>(w1, w1b);
  bucket_count_kernel<<<NCHK, 256, 0, stream>>>(ei, bucket_cnt);
  alloc_kernel<<<1, 512, 0, stream>>>(bucket_cnt, ebuf_base, csr_base, totals, ya, yb);
  scatter_kernel<<<NCHK, 256, 0, stream>>>(ei, ebuf_base, ebuf_fill, ebuf);
  bucket_sort_kernel<<<NB, 256, 0, stream>>>(ebuf, bucket_cnt, ebuf_base, csr_base,
                                             node_off, indeg, csr_src, perm);
  mlp_kernel<<<(NN + BM - 1) / BM, 256, 0, stream>>>(x, w1b, b1, w2, b2, indeg, htermp, ya);

  u32* yin = ya;
  u32* yout = yb;
  for (int k = 0; k < K_STEPS; ++k) {
    ppr_kernel<<<((size_t)NN * 4 + 255) / 256, 256, 0, stream>>>(node_off, indeg, perm,
                                                                 csr_src, yin, htermp, yout);
    u32* tmp = yin; yin = yout; yout = tmp;
  }
  out_kernel<<<((size_t)NN * 8 + 255) / 256, 256, 0, stream>>>(yin, indeg, (float*)d_out);
}

// Round 12
// 429.779 us; speedup vs baseline: 2.6051x; 1.0318x over previous
//
#include <hip/hip_runtime.h>
#include <stdint.h>

#define F_IN 512
#define F_HID 256
#define F_OUT 16
#define K_STEPS 10
#define NN 100000
#define EE 3200000
#define NB 391                     // ceil(NN/256) buckets of 256 nodes
#define CHUNK 8192
#define NCHK ((EE + CHUNK - 1) / CHUNK)   // 391

typedef float f32x4 __attribute__((ext_vector_type(4)));
typedef float f32x2 __attribute__((ext_vector_type(2)));
typedef short bf16x8 __attribute__((ext_vector_type(8)));
typedef unsigned int u32;
typedef unsigned int u32x4 __attribute__((ext_vector_type(4)));

__device__ __forceinline__ unsigned short f2bf(float f) {
  unsigned u = __builtin_bit_cast(unsigned, f);
  u += 0x7FFFu + ((u >> 16) & 1u);   // RNE
  return (unsigned short)(u >> 16);
}
__device__ __forceinline__ float bflo(u32 w) { return __builtin_bit_cast(float, w << 16); }
__device__ __forceinline__ float bfhi(u32 w) { return __builtin_bit_cast(float, w & 0xffff0000u); }

// ---- pass 1: per-bucket edge counts (LDS-aggregated); extra blocks convert w1 ----
__global__ __launch_bounds__(256) void bucket_count_kernel(const int* __restrict__ ei,
                                                           int* __restrict__ bucket_cnt,
                                                           const float* __restrict__ w1,
                                                           unsigned short* __restrict__ w1b) {
  if (blockIdx.x >= NCHK) {        // w1 -> bf16 tail blocks
    int i0 = (blockIdx.x - NCHK) * 256 + threadIdx.x;
    for (int i = i0; i < F_HID * F_IN; i += 8 * 256) w1b[i] = f2bf(w1[i]);
    return;
  }
  __shared__ int cntL[512];
  const int tid = threadIdx.x;
  cntL[tid] = 0; cntL[tid + 256] = 0;
  __syncthreads();
  const int base = blockIdx.x * CHUNK;
  int n = EE - base; if (n > CHUNK) n = CHUNK;
  for (int k = tid; k < n; k += 256) {
    int c = ei[EE + base + k];
    atomicAdd(&cntL[c >> 8], 1);
  }
  __syncthreads();
  if (cntL[tid]) atomicAdd(&bucket_cnt[tid], cntL[tid]);
  if (tid + 256 < NB && cntL[tid + 256]) atomicAdd(&bucket_cnt[tid + 256], cntL[tid + 256]);
}

// ---- pass 2: allocate ebuf (exact) and csr (pad8 + slack) regions; zero sentinel rows ----
__global__ void alloc_kernel(const int* __restrict__ bucket_cnt,
                             int* __restrict__ ebuf_base, int* __restrict__ csr_base,
                             int* __restrict__ totals,
                             u32* __restrict__ ya, u32* __restrict__ yb) {
  int t = threadIdx.x;
  if (t < NB) {
    int c = bucket_cnt[t];
    ebuf_base[t] = atomicAdd(&totals[0], c);
    csr_base[t]  = atomicAdd(&totals[1], ((c + 7) & ~7) + 2048);
  }
  if (t >= 400 && t < 408) ya[(size_t)NN * 8 + (t - 400)] = 0;
  if (t >= 408 && t < 416) yb[(size_t)NN * 8 + (t - 408)] = 0;
}

// ---- pass 3: bin edges into bucket-major ebuf with run-contiguous flushes ----
__global__ __launch_bounds__(256) void scatter_kernel(const int* __restrict__ ei,
                                                      const int* __restrict__ ebuf_base,
                                                      int* __restrict__ ebuf_fill,
                                                      u32* __restrict__ ebuf) {
  __shared__ u32 sA[512], sB[512], cnt0[512], fillI[512], runb[512];
  __shared__ u32 staged[CHUNK], gaddrL[CHUNK];
  const int tid = threadIdx.x;
  const int base = blockIdx.x * CHUNK;
  int n = EE - base; if (n > CHUNK) n = CHUNK;

  sA[tid] = 0; sA[tid + 256] = 0;
  fillI[tid] = 0; fillI[tid + 256] = 0;
  __syncthreads();
  for (int k = tid; k < n; k += 256) {
    int c = ei[EE + base + k];
    atomicAdd(&sA[c >> 8], 1u);
  }
  __syncthreads();
  cnt0[tid] = sA[tid]; cnt0[tid + 256] = sA[tid + 256];
  __syncthreads();
  u32* src = sA; u32* dst = sB;
  for (int off = 1; off < 512; off <<= 1) {
#pragma unroll
    for (int e = 0; e < 2; ++e) {
      int i = tid + e * 256;
      u32 v = src[i];
      if (i >= off) v += src[i - off];
      dst[i] = v;
    }
    __syncthreads();
    u32* tmp = src; src = dst; dst = tmp;
  }
#pragma unroll
  for (int e = 0; e < 2; ++e) {
    int b = tid + e * 256;
    if (b < NB && cnt0[b] > 0)
      runb[b] = (u32)ebuf_base[b] + (u32)atomicAdd(&ebuf_fill[b], (int)cnt0[b]);
  }
  __syncthreads();
  for (int k = tid; k < n; k += 256) {
    int r = ei[base + k];
    int c = ei[EE + base + k];
    int b = c >> 8;
    u32 excl = src[b] - cnt0[b];
    u32 slot = excl + atomicAdd(&fillI[b], 1u);
    staged[slot] = ((u32)r << 8) | (u32)(c & 255);
    gaddrL[slot] = runb[b] + (slot - excl);
  }
  __syncthreads();
  for (int s = tid; s < n; s += 256) ebuf[gaddrL[s]] = staged[s];
}

// ---- pass 4: per-bucket counting sort -> coalesced pad8-CSR + node_off/indeg + perm ----
__global__ __launch_bounds__(256) void bucket_sort_kernel(const u32* __restrict__ ebuf,
                                                          const int* __restrict__ bucket_cnt,
                                                          const int* __restrict__ ebuf_base,
                                                          const int* __restrict__ csr_base,
                                                          int* __restrict__ node_off,
                                                          int* __restrict__ indeg,
                                                          int* __restrict__ csr_src,
                                                          int* __restrict__ perm) {
  __shared__ int degL[256], exclL[256], scT[256], fillL[256];
  __shared__ int binc[64], bino[64], binf[64];
  __shared__ u32 sorted[12288];
  const int t = threadIdx.x;
  const int b = blockIdx.x;
  const int n0 = b << 8;
  const int nInB = (NN - n0) < 256 ? (NN - n0) : 256;
  const int cnt = bucket_cnt[b];
  const int ebase = ebuf_base[b];
  const int cbase = csr_base[b];

  degL[t] = 0;
  if (t < 64) { binc[t] = 0; binf[t] = 0; }
  for (int j = t; j < 12288; j += 256) sorted[j] = NN;   // sentinel prefill
  __syncthreads();
  for (int j = t; j < cnt; j += 256) atomicAdd(&degL[(int)(ebuf[ebase + j] & 255u)], 1);
  __syncthreads();
  int deg = degL[t];
  int pcnt = (deg + 7) & ~7;                             // pad to 8
  scT[t] = pcnt;
  __syncthreads();
  for (int off = 1; off < 256; off <<= 1) {
    int v = (t >= off) ? scT[t - off] : 0;
    __syncthreads();
    scT[t] += v;
    __syncthreads();
  }
  int excl = scT[t] - pcnt;
  exclL[t] = excl;
  fillL[t] = 0;
  int total = scT[255];
  if (t < nInB) {
    node_off[n0 + t] = cbase + excl;
    indeg[n0 + t] = deg;
  }
  int key = pcnt >> 3; if (key > 63) key = 63;
  if (t < nInB) atomicAdd(&binc[key], 1);
  __syncthreads();
  if (t == 0) { int s = 0; for (int k2 = 0; k2 < 64; ++k2) { bino[k2] = s; s += binc[k2]; } }
  __syncthreads();
  if (t < nInB) {
    int rank = bino[key] + atomicAdd(&binf[key], 1);
    perm[n0 + rank] = n0 + t;
  }
  for (int j = t; j < cnt; j += 256) {
    u32 e = ebuf[ebase + j];
    int nl = (int)(e & 255u);
    int pos = exclL[nl] + atomicAdd(&fillL[nl], 1);
    sorted[pos] = e >> 8;
  }
  __syncthreads();
  for (int j = t; j < total; j += 256) csr_src[cbase + j] = (int)sorted[j];
}

// ---- MFMA MLP: 64x256 tile, 4 waves x (64x64); writes y0 + hterm both packed bf16 ----
#define BM 64
#define BKC 32
#define NCH (F_IN / BKC)
#define AST 80
#define BST 80
#define ABYT (BM * AST)
#define BBYT (F_HID * BST)
#define PBYT (ABYT + BBYT)
__global__ __launch_bounds__(256) void mlp_kernel(const float* __restrict__ x,
                                                  const unsigned short* __restrict__ w1b,
                                                  const float* __restrict__ b1,
                                                  const float* __restrict__ w2,
                                                  const float* __restrict__ b2,
                                                  const int* __restrict__ indeg,
                                                  u32* __restrict__ htermp,
                                                  u32* __restrict__ y0) {
  __shared__ char lds[2 * PBYT];
  const int tid = threadIdx.x;
  const int wv = tid >> 6, l = tid & 63;
  const int lr = l & 15, lk = l >> 4;
  const int m0 = blockIdx.x * BM;

  const int rowA = tid >> 2, qA = tid & 3;
  int grA = m0 + rowA; if (grA >= NN) grA = NN - 1;
  const float* gA = x + (size_t)grA * F_IN + qA * 8;
  const int lofA = rowA * AST + qA * 16;
  const unsigned short* gB[4];
  int lofB[4];
#pragma unroll
  for (int ib = 0; ib < 4; ++ib) {
    int col = (tid >> 2) + 64 * ib, q = tid & 3;
    gB[ib]  = w1b + (size_t)col * F_IN + q * 8;
    lofB[ib] = ABYT + col * BST + q * 16;
  }

  f32x4 acc[4][4];
#pragma unroll
  for (int a = 0; a < 4; ++a)
#pragma unroll
    for (int b = 0; b < 4; ++b) acc[a][b] = (f32x4){0.f, 0.f, 0.f, 0.f};

  f32x4 pa0 = *(const f32x4*)(gA);
  f32x4 pa1 = *(const f32x4*)(gA + 4);
  bf16x8 rb[4];
#pragma unroll
  for (int ib = 0; ib < 4; ++ib) rb[ib] = *(const bf16x8*)(gB[ib]);
  {
    bf16x8 ab;
#pragma unroll
    for (int j = 0; j < 4; ++j) { ab[j] = (short)f2bf(pa0[j]); ab[j + 4] = (short)f2bf(pa1[j]); }
    *(bf16x8*)(lds + lofA) = ab;
#pragma unroll
    for (int ib = 0; ib < 4; ++ib) *(bf16x8*)(lds + lofB[ib]) = rb[ib];
  }
  __syncthreads();

  for (int c = 0; c < NCH; ++c) {
    char* buf = lds + (c & 1) * PBYT;
    if (c < NCH - 1) {
      pa0 = *(const f32x4*)(gA + (c + 1) * BKC);
      pa1 = *(const f32x4*)(gA + (c + 1) * BKC + 4);
#pragma unroll
      for (int ib = 0; ib < 4; ++ib) rb[ib] = *(const bf16x8*)(gB[ib] + (c + 1) * BKC);
    }
    bf16x8 af[4], bfr[4];
#pragma unroll
    for (int fm = 0; fm < 4; ++fm)
      af[fm] = *(const bf16x8*)(buf + (fm * 16 + lr) * AST + lk * 16);
#pragma unroll
    for (int fn = 0; fn < 4; ++fn)
      bfr[fn] = *(const bf16x8*)(buf + ABYT + (wv * 64 + fn * 16 + lr) * BST + lk * 16);
#pragma unroll
    for (int fm = 0; fm < 4; ++fm)
#pragma unroll
      for (int fn = 0; fn < 4; ++fn)
        acc[fm][fn] = __builtin_amdgcn_mfma_f32_16x16x32_bf16(af[fm], bfr[fn], acc[fm][fn],
                                                              0, 0, 0);
    if (c < NCH - 1) {
      char* nbuf = lds + ((c + 1) & 1) * PBYT;
      bf16x8 ab;
#pragma unroll
      for (int j = 0; j < 4; ++j) { ab[j] = (short)f2bf(pa0[j]); ab[j + 4] = (short)f2bf(pa1[j]); }
      *(bf16x8*)(nbuf + lofA) = ab;
#pragma unroll
      for (int ib = 0; ib < 4; ++ib) *(bf16x8*)(nbuf + lofB[ib]) = rb[ib];
    }
    __syncthreads();
  }

  unsigned short* h1p = (unsigned short*)lds;
  unsigned short* w2p = (unsigned short*)(lds + 64 * 264 * 2);
#pragma unroll
  for (int fn = 0; fn < 4; ++fn) {
    int col = wv * 64 + fn * 16 + lr;
    float bb = b1[col];
#pragma unroll
    for (int fm = 0; fm < 4; ++fm) {
#pragma unroll
      for (int r = 0; r < 4; ++r) {
        float v = acc[fm][fn][r] + bb;
        v = v > 0.f ? v : 0.f;
        h1p[(fm * 16 + lk * 4 + r) * 264 + col] = f2bf(v);
      }
    }
  }
  for (int i = tid; i < 16 * 256; i += 256) w2p[(i >> 8) * 264 + (i & 255)] = f2bf(w2[i]);
  __syncthreads();

  f32x4 acc2 = (f32x4){0.f, 0.f, 0.f, 0.f};
#pragma unroll
  for (int ks = 0; ks < 8; ++ks) {
    bf16x8 a2 = *(const bf16x8*)&h1p[(wv * 16 + lr) * 264 + ks * 32 + lk * 8];
    bf16x8 b2f = *(const bf16x8*)&w2p[lr * 264 + ks * 32 + lk * 8];
    acc2 = __builtin_amdgcn_mfma_f32_16x16x32_bf16(a2, b2f, acc2, 0, 0, 0);
  }
  float bb2 = b2[lr];
#pragma unroll
  for (int r = 0; r < 4; ++r) {
    int row = m0 + wv * 16 + lk * 4 + r;
    if (row < NN) {
      float d = (float)(indeg[row] + 1);
      float di = rsqrtf(d);
      float v = (acc2[r] + bb2) * di;            // y0 value for feature lr
      float vo = __shfl_xor(v, 1, 64);           // partner feature, same row
      if ((lr & 1) == 0) {
        y0[(size_t)row * 8 + (lr >> 1)] = (u32)f2bf(v) | ((u32)f2bf(vo) << 16);
        htermp[(size_t)row * 8 + (lr >> 1)] =
            (u32)f2bf(0.1f * v) | ((u32)f2bf(0.1f * vo) << 16);
      }
    }
  }
}

// ---- one PPR step: 4 lanes/node; csr prefetch distance 2; LAST fuses fp32 output ----
template <bool LAST>
__global__ __launch_bounds__(256) void ppr_kernel(const int* __restrict__ node_off,
                                                  const int* __restrict__ indeg,
                                                  const int* __restrict__ perm,
                                                  const int* __restrict__ csr_src,
                                                  const u32* __restrict__ yin,
                                                  const u32* __restrict__ htermp,
                                                  u32* __restrict__ yout,
                                                  float* __restrict__ zout) {
  int t = blockIdx.x * 256 + threadIdx.x;
  int i = t >> 2;
  if (i >= NN) return;
  const int sub = t & 3, eo = sub >> 1, hf = sub & 1;
  const int g = perm[i];
  const int deg = indeg[g], s0 = node_off[g];
  const int nblk = ((deg + 7) & ~7) >> 3;         // 8-edge super-blocks

  float al[4] = {0.f, 0.f, 0.f, 0.f};
  float ah[4] = {0.f, 0.f, 0.f, 0.f};

  const u32* cp = (const u32*)csr_src + s0 + eo * 4;
  u32x4 s0v, s1v;
  if (nblk > 0) s0v = *(const u32x4*)cp;
  if (nblk > 1) s1v = *(const u32x4*)(cp + 8);
  for (int b = 0; b < nblk; ++b) {
    u32x4 s2v;
    if (b + 2 < nblk) s2v = *(const u32x4*)(cp + (size_t)(b + 2) * 8);
#pragma unroll
    for (int j = 0; j < 4; ++j) {
      u32x4 v = *(const u32x4*)(yin + (size_t)s0v[j] * 8 + hf * 4);
      al[0] += bflo(v[0]); ah[0] += bfhi(v[0]);
      al[1] += bflo(v[1]); ah[1] += bfhi(v[1]);
      al[2] += bflo(v[2]); ah[2] += bfhi(v[2]);
      al[3] += bflo(v[3]); ah[3] += bfhi(v[3]);
    }
    s0v = s1v; s1v = s2v;
  }
  // combine the two eo lanes (lane bit 1)
#pragma unroll
  for (int j = 0; j < 4; ++j) {
    al[j] += __shfl_xor(al[j], 2, 64);
    ah[j] += __shfl_xor(ah[j], 2, 64);
  }
  if (eo == 0) {
    u32x4 sv = *(const u32x4*)(yin + (size_t)g * 8 + hf * 4);
    u32x4 hp = *(const u32x4*)(htermp + (size_t)g * 8 + hf * 4);
    float ra = 0.9f * __builtin_amdgcn_rcpf((float)(deg + 1));
    if (LAST) {
      float sd = sqrtf((float)(deg + 1));
      f32x4 o0, o1;
#pragma unroll
      for (int j = 0; j < 4; ++j) {
        float lo = (ra * (al[j] + bflo(sv[j])) + bflo(hp[j])) * sd;
        float hi = (ra * (ah[j] + bfhi(sv[j])) + bfhi(hp[j])) * sd;
        if (j < 2) { o0[2 * j] = lo; o0[2 * j + 1] = hi; }
        else       { o1[2 * j - 4] = lo; o1[2 * j - 3] = hi; }
      }
      *(f32x4*)(zout + (size_t)g * F_OUT + hf * 8)     = o0;
      *(f32x4*)(zout + (size_t)g * F_OUT + hf * 8 + 4) = o1;
    } else {
      u32x4 o;
#pragma unroll
      for (int j = 0; j < 4; ++j) {
        float lo = ra * (al[j] + bflo(sv[j])) + bflo(hp[j]);
        float hi = ra * (ah[j] + bfhi(sv[j])) + bfhi(hp[j]);
        o[j] = (u32)f2bf(lo) | ((u32)f2bf(hi) << 16);
      }
      *(u32x4*)(yout + (size_t)g * 8 + hf * 4) = o;
    }
  }
}

extern "C" void kernel_launch(void* const* d_in, const int* in_sizes, int n_in,
                              void* d_out, int out_size, void* d_ws, size_t ws_size,
                              hipStream_t stream) {
  const float* x  = (const float*)d_in[0];
  const float* w1 = (const float*)d_in[1];
  const float* b1 = (const float*)d_in[2];
  const float* w2 = (const float*)d_in[3];
  const float* b2 = (const float*)d_in[4];
  const int*   ei = (const int*)d_in[5];

  char* p = (char*)d_ws;
  auto alloc = [&](size_t bytes) {
    char* r = p;
    p += (bytes + 255) & ~(size_t)255;
    return r;
  };
  u32* htermp = (u32*)alloc((size_t)NN * 8 * 4);
  u32* ya = (u32*)alloc((size_t)(NN + 1) * 8 * 4);
  u32* yb = (u32*)alloc((size_t)(NN + 1) * 8 * 4);
  unsigned short* w1b = (unsigned short*)alloc((size_t)F_HID * F_IN * 2);
  int* aux = (int*)alloc(((size_t)2 * NB + 2) * 4);    // bucket_cnt | ebuf_fill | totals[2]
  int* bucket_cnt = aux;
  int* ebuf_fill  = aux + NB;
  int* totals     = aux + 2 * NB;
  int* ebuf_base = (int*)alloc((size_t)NB * 4);
  int* csr_base  = (int*)alloc((size_t)NB * 4);
  int* node_off  = (int*)alloc((size_t)NN * 4);
  int* indeg     = (int*)alloc((size_t)NN * 4);
  int* perm      = (int*)alloc((size_t)NN * 4);
  u32* ebuf      = (u32*)alloc((size_t)EE * 4);
  int* csr_src   = (int*)alloc(((size_t)EE + (size_t)NB * 2048 + 64) * 4);

  hipMemsetAsync(aux, 0, ((size_t)2 * NB + 2) * 4, stream);

  bucket_count_kernel<<<NCHK + 8, 256, 0, stream>>>(ei, bucket_cnt, w1, w1b);
  alloc_kernel<<<1, 512, 0, stream>>>(bucket_cnt, ebuf_base, csr_base, totals, ya, yb);
  scatter_kernel<<<NCHK, 256, 0, stream>>>(ei, ebuf_base, ebuf_fill, ebuf);
  bucket_sort_kernel<<<NB, 256, 0, stream>>>(ebuf, bucket_cnt, ebuf_base, csr_base,
                                             node_off, indeg, csr_src, perm);
  mlp_kernel<<<(NN + BM - 1) / BM, 256, 0, stream>>>(x, w1b, b1, w2, b2, indeg, htermp, ya);

  u32* yin = ya;
  u32* yout = yb;
  const int pgrid = (int)(((size_t)NN * 4 + 255) / 256);
  for (int k = 0; k < K_STEPS - 1; ++k) {
    ppr_kernel<false><<<pgrid, 256, 0, stream>>>(node_off, indeg, perm, csr_src,
                                                 yin, htermp, yout, nullptr);
    u32* tmp = yin; yin = yout; yout = tmp;
  }
  ppr_kernel<true><<<pgrid, 256, 0, stream>>>(node_off, indeg, perm, csr_src,
                                              yin, htermp, yout, (float*)d_out);
}